// Round 7
// baseline (740.018 us; speedup 1.0000x reference)
//
#include <hip/hip_runtime.h>

// Problem constants
#define S_LEN   4096
#define D_DIM   1024
#define WIN_    256
#define STRIDE_ 128
#define GLOB_   16
#define SCALE_F 0.03125f   // 1/sqrt(1024)
#define EPS_F   1e-5f

typedef __bf16 bf16x8 __attribute__((ext_vector_type(8)));
typedef float  f32x4  __attribute__((ext_vector_type(4)));

__device__ __forceinline__ float b2f(unsigned short u) {
    union { unsigned int i; float f; } c; c.i = ((unsigned int)u) << 16; return c.f;
}
__device__ __forceinline__ unsigned short f2bf(float f) {
    union { float f; unsigned int i; } c; c.f = f;
    unsigned int u = c.i;
    u += 0x7fffu + ((u >> 16) & 1u);   // round-to-nearest-even
    return (unsigned short)(u >> 16);
}

// async global->LDS, 16B per lane (dest = wave-uniform base + lane*16)
__device__ __forceinline__ void gld_lds16(const void* g, void* l) {
    __builtin_amdgcn_global_load_lds(
        (const __attribute__((address_space(1))) unsigned int*)g,
        (__attribute__((address_space(3))) unsigned int*)l, 16, 0, 0);
}

// ---------------- block reduction helper (256 threads = 4 waves) -----------
__device__ __forceinline__ float blk_sum(float v, float* red, int tid) {
    int lane = tid & 63, wv = tid >> 6;
    #pragma unroll
    for (int m = 32; m >= 1; m >>= 1) v += __shfl_xor(v, m, 64);
    __syncthreads();
    if (lane == 0) red[wv] = v;
    __syncthreads();
    return red[0] + red[1] + red[2] + red[3];
}

// ---------------- LN1 full: mu/rs + xb = bf16(LN(tok)*g1+b1) ---------------
__global__ __launch_bounds__(256) void ln_full_kernel(
    const float* __restrict__ in, float* __restrict__ mu, float* __restrict__ rs,
    const float* __restrict__ g, const float* __restrict__ bb,
    unsigned short* __restrict__ xb) {
    __shared__ float red[4];
    int row = blockIdx.x, tid = threadIdx.x;
    size_t off = (size_t)row * D_DIM + tid * 4;
    float4 r = *(const float4*)(in + off);
    float s = blk_sum(r.x + r.y + r.z + r.w, red, tid);
    float mean = s * (1.0f / 1024.0f);
    float d0 = r.x - mean, d1 = r.y - mean, d2 = r.z - mean, d3 = r.w - mean;
    float s2 = blk_sum(d0*d0 + d1*d1 + d2*d2 + d3*d3, red, tid);
    float rstd = rsqrtf(s2 * (1.0f / 1024.0f) + EPS_F);
    if (tid == 0) { mu[row] = mean; rs[row] = rstd; }
    float4 gr = *(const float4*)(g  + tid * 4);
    float4 br = *(const float4*)(bb + tid * 4);
    ushort4 o;
    o.x = f2bf(d0 * rstd * gr.x + br.x);
    o.y = f2bf(d1 * rstd * gr.y + br.y);
    o.z = f2bf(d2 * rstd * gr.z + br.z);
    o.w = f2bf(d3 * rstd * gr.w + br.w);
    *(ushort4*)(xb + off) = o;
}

// ---------------- LN2 in place (fp32, block-local rows) --------------------
__global__ __launch_bounds__(256) void ln2_inplace_kernel(
    float* __restrict__ data, const float* __restrict__ g,
    const float* __restrict__ bb) {
    __shared__ float red[4];
    int row = blockIdx.x, tid = threadIdx.x;
    size_t off = (size_t)row * D_DIM + tid * 4;
    float4 v = *(const float4*)(data + off);
    float s = blk_sum(v.x + v.y + v.z + v.w, red, tid);
    float mean = s * (1.0f / 1024.0f);
    float d0 = v.x - mean, d1 = v.y - mean, d2 = v.z - mean, d3 = v.w - mean;
    float s2 = blk_sum(d0*d0 + d1*d1 + d2*d2 + d3*d3, red, tid);
    float rstd = rsqrtf(s2 * (1.0f / 1024.0f) + EPS_F);
    float4 gr = *(const float4*)(g  + tid * 4);
    float4 br = *(const float4*)(bb + tid * 4);
    float4 o;
    o.x = d0 * rstd * gr.x + br.x;
    o.y = d1 * rstd * gr.y + br.y;
    o.z = d2 * rstd * gr.z + br.z;
    o.w = d3 * rstd * gr.w + br.w;
    *(float4*)(data + off) = o;
}

// ---------------- transpose+convert: fp32 [1024][1024] -> bf16 T -----------
__global__ __launch_bounds__(256) void transpose_cvt(
    const float* __restrict__ in, unsigned short* __restrict__ outp) {
    __shared__ unsigned short tile[32][33];
    int tid = threadIdx.x;
    int tx = tid & 31, ty = tid >> 5;          // 32 x 8
    int bx = blockIdx.x * 32, by = blockIdx.y * 32;
    #pragma unroll
    for (int r = 0; r < 32; r += 8)
        tile[ty + r][tx] = f2bf(in[(size_t)(by + ty + r) * 1024 + bx + tx]);
    __syncthreads();
    #pragma unroll
    for (int r = 0; r < 32; r += 8)
        outp[(size_t)(bx + ty + r) * 1024 + by + tx] = tile[tx][ty + r];
}

// ---------------- bf16 1024x1024 transpose ---------------------------------
__global__ __launch_bounds__(256) void transpose1024(
    const unsigned short* __restrict__ in, unsigned short* __restrict__ outp) {
    __shared__ unsigned short tile[32][33];
    int tid = threadIdx.x;
    int tx = tid & 31, ty = tid >> 5;
    int bx = blockIdx.x * 32, by = blockIdx.y * 32;
    #pragma unroll
    for (int r = 0; r < 32; r += 8)
        tile[ty + r][tx] = in[(size_t)(by + ty + r) * 1024 + bx + tx];
    __syncthreads();
    #pragma unroll
    for (int r = 0; r < 32; r += 8)
        outp[(size_t)(bx + ty + r) * 1024 + by + tx] = tile[tx][ty + r];
}

// ---------------- fused transpose + LN1: tokens -> X16 (MFMA-tiled) --------
// X16[b][sT][nT][nl][sl]: 16x16 tile (s-contiguous rows of 16), 512B/tile.
// element (b,s,n) at b*4194304 + ((s>>4)*64 + (n>>4))*256 + (n&15)*16 + (s&15)
__global__ __launch_bounds__(256) void transln16_kernel(
    const float* __restrict__ tok, const float* __restrict__ mu,
    const float* __restrict__ rs, const float* __restrict__ g,
    const float* __restrict__ bb, unsigned short* __restrict__ X16) {
    __shared__ unsigned short Lt[32][36];   // [n_local][s_local], pad 36 for 8B align
    int tid = threadIdx.x;
    int tx = tid & 31, ty = tid >> 5;      // 32 x 8
    int s0 = blockIdx.x * 32;              // seq within batch
    int n0 = blockIdx.y * 32;              // feature
    int b  = blockIdx.z;
    float gv = g[n0 + tx], bv = bb[n0 + tx];
    #pragma unroll
    for (int r = 0; r < 32; r += 8) {
        int grow = (b << 12) + s0 + ty + r;
        float v = tok[(size_t)grow * 1024 + n0 + tx];
        Lt[tx][ty + r] = f2bf((v - mu[grow]) * rs[grow] * gv + bv);
    }
    __syncthreads();
    int tt  = tid >> 6;                    // wave -> one 16x16 tile
    int sTl = tt >> 1, nTl = tt & 1;
    int idx = tid & 63;
    int nl  = idx >> 2, so4 = (idx & 3) << 2;   // 4 s-elems = 8B per thread
    uint2 v = *(const uint2*)&Lt[nTl * 16 + nl][sTl * 16 + so4];
    size_t off = (size_t)b * 4194304 +
        (((size_t)(((s0 >> 4) + sTl) * 64 + (n0 >> 4) + nTl)) << 8) +
        (nl << 4) + so4;
    *(uint2*)(X16 + off) = v;
}

// ---------------- small GEMM: Wfused = bf16(Wv @ Wo) -----------------------
__global__ __launch_bounds__(256) void gemm_small(
    const float* __restrict__ A32, const float* __restrict__ W32,
    unsigned short* __restrict__ C16) {
    const int K = 1024, N = 1024;
    __shared__ __align__(16) unsigned short As[64][40];
    __shared__ __align__(16) unsigned short Bs[64][40];
    int tid  = threadIdx.x;
    int lane = tid & 63, wv = tid >> 6;
    int lm   = lane & 15, quad = lane >> 4;
    int m0 = blockIdx.y * 64, n0 = blockIdx.x * 64;
    int srow = tid >> 2, scg = tid & 3;
    int bk   = tid >> 3, bn  = (tid & 7) * 8;

    f32x4 acc[4] = {};
    for (int k0 = 0; k0 < K; k0 += 32) {
        const float* ap = A32 + (size_t)(m0 + srow) * K + k0 + scg * 8;
        float4 p = *(const float4*)(ap);
        float4 q = *(const float4*)(ap + 4);
        union { uint4 u; unsigned short s[8]; } w;
        w.s[0]=f2bf(p.x); w.s[1]=f2bf(p.y); w.s[2]=f2bf(p.z); w.s[3]=f2bf(p.w);
        w.s[4]=f2bf(q.x); w.s[5]=f2bf(q.y); w.s[6]=f2bf(q.z); w.s[7]=f2bf(q.w);
        *(uint4*)&As[srow][scg * 8] = w.u;

        const float* wp = W32 + (size_t)(k0 + bk) * N + n0 + bn;
        float4 a = *(const float4*)wp, b = *(const float4*)(wp + 4);
        float wvv[8] = {a.x,a.y,a.z,a.w,b.x,b.y,b.z,b.w};
        #pragma unroll
        for (int e = 0; e < 8; ++e) Bs[bn + e][bk] = f2bf(wvv[e]);
        __syncthreads();
        bf16x8 af = *(const bf16x8*)&As[wv * 16 + lm][quad * 8];
        #pragma unroll
        for (int t = 0; t < 4; ++t) {
            bf16x8 bfr = *(const bf16x8*)&Bs[t * 16 + lm][quad * 8];
            acc[t] = __builtin_amdgcn_mfma_f32_16x16x32_bf16(af, bfr, acc[t], 0, 0, 0);
        }
        __syncthreads();
    }
    #pragma unroll
    for (int t = 0; t < 4; ++t) {
        int col = n0 + t * 16 + lm;
        #pragma unroll
        for (int r = 0; r < 4; ++r) {
            int row = m0 + wv * 16 + quad * 4 + r;
            C16[(size_t)row * N + col] = f2bf(acc[t][r]);
        }
    }
}

// ---------------- m97-style 128x128 GEMM: C = A[bf16] @ BT[bf16]^T ---------
// (round-4 version: single-buffer; dbuf experiment regressed)
template <bool EPI>
__global__ __launch_bounds__(256) void gemm128(
    const unsigned short* __restrict__ A, const unsigned short* __restrict__ BT,
    unsigned short* __restrict__ C16, float* __restrict__ Cres,
    const float* __restrict__ tok) {
    const int K = 1024, N = 1024;
    __shared__ __align__(16) unsigned short As[4096];  // 4 octets x 128 rows x 8
    __shared__ __align__(16) unsigned short Bs[4096];
    int tid = threadIdx.x, lane = tid & 63, wv = tid >> 6;
    int lm = lane & 15, quad = lane >> 4;
    int wr = wv >> 1, wc = wv & 1;
    // XCD swizzle (dispatch order: x fastest). 1024 = 8*128, bijective.
    int flat = blockIdx.y * 8 + blockIdx.x;
    int logical = ((flat & 7) << 7) | (flat >> 3);
    int m0 = (logical >> 3) * 128, n0 = (logical & 7) * 128;

    f32x4 acc[4][4] = {};

    const unsigned short* ga0 = A  + (size_t)(m0 + lane) * K + wv * 8;
    const unsigned short* ga1 = A  + (size_t)(m0 + 64 + lane) * K + wv * 8;
    const unsigned short* gb0 = BT + (size_t)(n0 + lane) * K + wv * 8;
    const unsigned short* gb1 = BT + (size_t)(n0 + 64 + lane) * K + wv * 8;
    unsigned short* la0 = &As[wv * 1024 + lane * 8];
    unsigned short* la1 = &As[wv * 1024 + 512 + lane * 8];
    unsigned short* lb0 = &Bs[wv * 1024 + lane * 8];
    unsigned short* lb1 = &Bs[wv * 1024 + 512 + lane * 8];

    for (int k0 = 0; k0 < K; k0 += 32) {
        gld_lds16(ga0 + k0, la0);
        gld_lds16(ga1 + k0, la1);
        gld_lds16(gb0 + k0, lb0);
        gld_lds16(gb1 + k0, lb1);
        __syncthreads();
        bf16x8 af[4], bfr[4];
        #pragma unroll
        for (int t = 0; t < 4; ++t) {
            af[t]  = *(const bf16x8*)&As[quad * 1024 + (wr * 64 + t * 16 + lm) * 8];
            bfr[t] = *(const bf16x8*)&Bs[quad * 1024 + (wc * 64 + t * 16 + lm) * 8];
        }
        #pragma unroll
        for (int mt = 0; mt < 4; ++mt)
            #pragma unroll
            for (int nt = 0; nt < 4; ++nt)
                acc[mt][nt] = __builtin_amdgcn_mfma_f32_16x16x32_bf16(
                    af[mt], bfr[nt], acc[mt][nt], 0, 0, 0);
        __syncthreads();
    }
    #pragma unroll
    for (int mt = 0; mt < 4; ++mt) {
        #pragma unroll
        for (int nt = 0; nt < 4; ++nt) {
            int col = n0 + wc * 64 + nt * 16 + lm;
            #pragma unroll
            for (int r = 0; r < 4; ++r) {
                int row = m0 + wr * 64 + mt * 16 + quad * 4 + r;
                size_t idx = (size_t)row * N + col;
                if (EPI) Cres[idx] = tok[idx] + 0.1f * acc[mt][nt][r];
                else     C16[idx]  = f2bf(acc[mt][nt][r]);
            }
        }
    }
}

// ---------------- MFMA sparse attention: 16 queries per block --------------
// Tiles (all 16-aligned, distinct): window [max(0,i0-256)..i0], strided
// i0-128t (t>=3, >=16), global tile 0 (if not already in window).
// Per-element mask applied when writing scores.  P kept bf16 in LDS.
// PV uses X16 tiled layout (16 lines/instr, full-line use).
// Swizzle: two levels.
//  XCD level (frozen, round 3): XCD 2b+0 <- batch b tiles [0,64)u[192,256),
//  XCD 2b+1 <- batch b tiles [64,192). Equal XCD work within 2%.
//  CU level (round 6): slot quads {4g..4g+3} -> constant work-sum tiles:
//  ptyp1 -> {64+g,191-g,96+g,159-g}, ptyp0 -> {g,255-g,63-g,192+g}.
// NOTE: NO min-occupancy launch_bounds — (256,4) capped VGPR and spilled
// oacc[16] to scratch (VGPR 64, WRITE_SIZE 3x, dur +53us). Plain (256)
// compiles to VGPR 128 = 4 blocks/CU with zero spill.
#define NT_MAX 48
#define SCROW  776    // 48*16 + 8 pad (elems)
__global__ __launch_bounds__(256) void attn16_kernel(
    const unsigned short* __restrict__ Q, const unsigned short* __restrict__ K,
    const unsigned short* __restrict__ XT, unsigned short* __restrict__ Ao) {
    __shared__ __align__(16) unsigned short Ps[16 * SCROW];
    int tid = threadIdx.x, lane = tid & 63, wv = tid >> 6;
    int lm = lane & 15, quad = lane >> 4;
    // two-level balanced swizzle (bijective over 1024 blocks)
    int bxr = blockIdx.x;
    int xcd = bxr & 7;
    int sl  = bxr >> 3;                  // 0..127 slot within XCD
    int batch = xcd >> 1;
    int ptyp  = xcd & 1;
    int g = sl >> 2, p = sl & 3;         // CU-group 0..31, position 0..3
    int t;
    if (ptyp) t = (p == 0) ? 64 + g : (p == 1) ? 191 - g
                 : (p == 2) ? 96 + g : 159 - g;
    else      t = (p == 0) ? g       : (p == 1) ? 255 - g
                 : (p == 2) ? 63 - g : 192 + g;
    int bx = batch * 256 + t;
    int b  = bx >> 8;
    int i0 = (bx & 255) << 4;
    int rowbase = (b << 12) + i0;
    // tile bookkeeping (uniform)
    int wlo = i0 - 256; if (wlo < 0) wlo = 0;
    int nwin = ((i0 - wlo) >> 4) + 1;
    int tmax = (i0 - 16) / 128;              // trunc; i0=0 -> 0
    int nstr = tmax - 2; if (nstr < 0) nstr = 0;
    int nglob = (wlo > 0) ? 1 : 0;
    int ntiles = nwin + nstr + nglob;
    int ntp = (ntiles + 3) & ~3;

    // per-lane Q row pointer (a-frag source; row = rowbase + lm)
    const unsigned short* Qg = Q + (size_t)(rowbase + lm) * 1024 + quad * 8;

    // ---- phase 1: score tiles (QK^T), masked write to Ps ----
    const unsigned short* Kbp = K + (((size_t)b << 12) << 10);
    for (int tg = wv * 4; tg < ntp; tg += 16) {
        f32x4 acc[4] = {};
        int tb[4];
        #pragma unroll
        for (int c = 0; c < 4; ++c) {
            int t2 = tg + c, base = 0;
            if (t2 < nwin) base = wlo + (t2 << 4);
            else if (t2 - nwin < nstr) base = i0 - 128 * (3 + (t2 - nwin));
            tb[c] = base;                     // global / padded -> 0
        }
        for (int k0 = 0; k0 < 1024; k0 += 32) {
            bf16x8 a = *(const bf16x8*)(Qg + k0);
            #pragma unroll
            for (int c = 0; c < 4; ++c) {
                bf16x8 bb = *(const bf16x8*)(Kbp +
                    (size_t)(tb[c] + lm) * 1024 + k0 + quad * 8);
                acc[c] = __builtin_amdgcn_mfma_f32_16x16x32_bf16(a, bb, acc[c], 0, 0, 0);
            }
        }
        #pragma unroll
        for (int c = 0; c < 4; ++c) {
            int t2 = tg + c;
            int j = tb[c] + lm;
            bool pad = (t2 >= ntiles);
            #pragma unroll
            for (int r = 0; r < 4; ++r) {
                int i = i0 + quad * 4 + r;
                int diff = i - j;
                bool ok = !pad && (j <= i) &&
                          (diff < 256 || (diff & 127) == 0 || j < 16);
                Ps[(quad * 4 + r) * SCROW + (t2 << 4) + lm] =
                    f2bf(ok ? acc[c][r] : -1e30f);
            }
        }
    }
    __syncthreads();

    // ---- phase 2: softmax on rows wv*4 .. wv*4+3 ----
    int ncol = ntp << 4;
    for (int q = wv * 4; q < wv * 4 + 4; ++q) {
        unsigned short* row = &Ps[q * SCROW];
        float mx = -1e30f;
        for (int c = lane; c < ncol; c += 64) mx = fmaxf(mx, b2f(row[c]));
        #pragma unroll
        for (int m = 32; m >= 1; m >>= 1) mx = fmaxf(mx, __shfl_xor(mx, m, 64));
        float sm = 0.f;
        for (int c = lane; c < ncol; c += 64)
            sm += __expf(SCALE_F * (b2f(row[c]) - mx));
        #pragma unroll
        for (int m = 32; m >= 1; m >>= 1) sm += __shfl_xor(sm, m, 64);
        float inv = 1.0f / sm;
        for (int c = lane; c < ncol; c += 64)
            row[c] = f2bf(__expf(SCALE_F * (b2f(row[c]) - mx)) * inv);
    }
    __syncthreads();

    // ---- phase 3: O = P @ X16  (wave owns 256 cols = n-tiles nT0..nT0+15) --
    int n0w = wv * 256;
    int nT0 = wv << 4;
    const unsigned short* Xb = XT + (size_t)b * 4194304;
    int octet = quad & 1, tsel = quad >> 1;
    f32x4 oacc[16] = {};
    int nch = ntp >> 1;
    for (int c = 0; c < nch; ++c) {
        int t0 = 2 * c, t1 = 2 * c + 1;
        int b0 = (t0 < nwin) ? wlo + (t0 << 4)
               : ((t0 - nwin < nstr) ? i0 - 128 * (3 + t0 - nwin) : 0);
        int b1 = (t1 < nwin) ? wlo + (t1 << 4)
               : ((t1 - nwin < nstr) ? i0 - 128 * (3 + t1 - nwin) : 0);
        bf16x8 a = *(const bf16x8*)&Ps[lm * SCROW + (c << 5) + quad * 8];
        int sT = (tsel ? b1 : b0) >> 4;
        const unsigned short* xp = Xb + (((size_t)(sT * 64 + nT0)) << 8)
                                      + (lm << 4) + (octet << 3);
        #pragma unroll
        for (int nt = 0; nt < 16; ++nt) {
            bf16x8 bb2 = *(const bf16x8*)(xp + (nt << 8));
            oacc[nt] = __builtin_amdgcn_mfma_f32_16x16x32_bf16(a, bb2, oacc[nt], 0, 0, 0);
        }
    }
    #pragma unroll
    for (int nt = 0; nt < 16; ++nt) {
        int col = n0w + nt * 16 + lm;
        #pragma unroll
        for (int r = 0; r < 4; ++r) {
            int row = rowbase + quad * 4 + r;
            Ao[(size_t)row * 1024 + col] = f2bf(oacc[nt][r]);
        }
    }
}

// ---------------------------------------------------------------------------
extern "C" void kernel_launch(void* const* d_in, const int* in_sizes, int n_in,
                              void* d_out, int out_size, void* d_ws, size_t ws_size,
                              hipStream_t stream) {
    const float* tokens = (const float*)d_in[0];
    const float* Wq = (const float*)d_in[1];
    const float* Wk = (const float*)d_in[2];
    const float* Wv = (const float*)d_in[3];
    const float* Wo = (const float*)d_in[4];
    const float* g1 = (const float*)d_in[5];
    const float* b1 = (const float*)d_in[6];
    const float* g2 = (const float*)d_in[7];
    const float* b2 = (const float*)d_in[8];
    float* out = (float*)d_out;
    char* ws = (char*)d_ws;

    // ws (41MB):
    //   mu @0 (64KB), rs @64KB, WqT @1MB, WkT @3MB, Wfused @5MB, WfT @7MB,
    //   Q bf16 @9MB..41MB  -> attnX written in place
    // d_out (64MB fp32) as staging:
    //   xb bf16 @[0:32MB)  -> overwritten by X16 after Q/K gemms
    //   K  bf16 @[32:64MB)
    // then out-gemm overwrites all of d_out with fp32 residual; LN2 in place.
    const size_t MB = 1048576;
    float* mu = (float*)(ws);
    float* rs = (float*)(ws + 65536);
    unsigned short* WqT    = (unsigned short*)(ws + 1 * MB);
    unsigned short* WkT    = (unsigned short*)(ws + 3 * MB);
    unsigned short* Wfused = (unsigned short*)(ws + 5 * MB);
    unsigned short* WfT    = (unsigned short*)(ws + 7 * MB);
    unsigned short* Qb     = (unsigned short*)(ws + 9 * MB);
    unsigned short* xb     = (unsigned short*)d_out;
    unsigned short* X16    = (unsigned short*)d_out;   // overwrites xb later
    unsigned short* Kb     = (unsigned short*)d_out + 16777216;
    unsigned short* attnX  = Qb;

    dim3 b256(256);
    const int ROWS = 4 * S_LEN;           // 16384
    dim3 tg(32, 32);
    dim3 gsmall(16, 16);
    dim3 g128(8, 128);                    // N/128 x M/128
    dim3 gtl(128, 32, 4);                 // transLN16: s-tiles x n-tiles x batch

    // 1. LN1: stats + xb (row-major)
    ln_full_kernel<<<ROWS, b256, 0, stream>>>(tokens, mu, rs, g1, b1, xb);
    // 2. weight prep
    transpose_cvt<<<tg, b256, 0, stream>>>(Wq, WqT);
    transpose_cvt<<<tg, b256, 0, stream>>>(Wk, WkT);
    gemm_small<<<gsmall, b256, 0, stream>>>(Wv, Wo, Wfused);
    transpose1024<<<tg, b256, 0, stream>>>(Wfused, WfT);
    // 3. Q = xb@Wq, K = xb@Wk
    gemm128<false><<<g128, b256, 0, stream>>>(xb, WqT, Qb, nullptr, nullptr);
    gemm128<false><<<g128, b256, 0, stream>>>(xb, WkT, Kb, nullptr, nullptr);
    // 4. X16 = tiled(LN1(tokens)) per batch (overwrites xb; reads tokens)
    transln16_kernel<<<gtl, b256, 0, stream>>>(tokens, mu, rs, g1, b1, X16);
    // 5. MFMA sparse attention (attnX over Q)
    attn16_kernel<<<1024, b256, 0, stream>>>(Qb, Kb, X16, attnX);
    // 6. out = tokens + 0.1*(attnX @ Wfused)
    gemm128<true><<<g128, b256, 0, stream>>>(attnX, WfT, nullptr, out, tokens);
    // 7. LN2 in place
    ln2_inplace_kernel<<<ROWS, b256, 0, stream>>>(out, g2, b2);
}

// Round 8
// 664.613 us; speedup vs baseline: 1.1135x; 1.1135x over previous
//
#include <hip/hip_runtime.h>

// Problem constants
#define S_LEN   4096
#define D_DIM   1024
#define WIN_    256
#define STRIDE_ 128
#define GLOB_   16
#define SCALE_F 0.03125f   // 1/sqrt(1024)
#define EPS_F   1e-5f

typedef __bf16 bf16x8 __attribute__((ext_vector_type(8)));
typedef float  f32x4  __attribute__((ext_vector_type(4)));

__device__ __forceinline__ float b2f(unsigned short u) {
    union { unsigned int i; float f; } c; c.i = ((unsigned int)u) << 16; return c.f;
}
__device__ __forceinline__ unsigned short f2bf(float f) {
    union { float f; unsigned int i; } c; c.f = f;
    unsigned int u = c.i;
    u += 0x7fffu + ((u >> 16) & 1u);   // round-to-nearest-even
    return (unsigned short)(u >> 16);
}

// async global->LDS, 16B per lane (dest = wave-uniform base + lane*16)
__device__ __forceinline__ void gld_lds16(const void* g, void* l) {
    __builtin_amdgcn_global_load_lds(
        (const __attribute__((address_space(1))) unsigned int*)g,
        (__attribute__((address_space(3))) unsigned int*)l, 16, 0, 0);
}

// ---------------- block reduction helper (256 threads = 4 waves) -----------
__device__ __forceinline__ float blk_sum(float v, float* red, int tid) {
    int lane = tid & 63, wv = tid >> 6;
    #pragma unroll
    for (int m = 32; m >= 1; m >>= 1) v += __shfl_xor(v, m, 64);
    __syncthreads();
    if (lane == 0) red[wv] = v;
    __syncthreads();
    return red[0] + red[1] + red[2] + red[3];
}

// ---------------- LN1 full: mu/rs + xb = bf16(LN(tok)*g1+b1) ---------------
__global__ __launch_bounds__(256) void ln_full_kernel(
    const float* __restrict__ in, float* __restrict__ mu, float* __restrict__ rs,
    const float* __restrict__ g, const float* __restrict__ bb,
    unsigned short* __restrict__ xb) {
    __shared__ float red[4];
    int row = blockIdx.x, tid = threadIdx.x;
    size_t off = (size_t)row * D_DIM + tid * 4;
    float4 r = *(const float4*)(in + off);
    float s = blk_sum(r.x + r.y + r.z + r.w, red, tid);
    float mean = s * (1.0f / 1024.0f);
    float d0 = r.x - mean, d1 = r.y - mean, d2 = r.z - mean, d3 = r.w - mean;
    float s2 = blk_sum(d0*d0 + d1*d1 + d2*d2 + d3*d3, red, tid);
    float rstd = rsqrtf(s2 * (1.0f / 1024.0f) + EPS_F);
    if (tid == 0) { mu[row] = mean; rs[row] = rstd; }
    float4 gr = *(const float4*)(g  + tid * 4);
    float4 br = *(const float4*)(bb + tid * 4);
    ushort4 o;
    o.x = f2bf(d0 * rstd * gr.x + br.x);
    o.y = f2bf(d1 * rstd * gr.y + br.y);
    o.z = f2bf(d2 * rstd * gr.z + br.z);
    o.w = f2bf(d3 * rstd * gr.w + br.w);
    *(ushort4*)(xb + off) = o;
}

// ---------------- LN2 in place (fp32, block-local rows) --------------------
__global__ __launch_bounds__(256) void ln2_inplace_kernel(
    float* __restrict__ data, const float* __restrict__ g,
    const float* __restrict__ bb) {
    __shared__ float red[4];
    int row = blockIdx.x, tid = threadIdx.x;
    size_t off = (size_t)row * D_DIM + tid * 4;
    float4 v = *(const float4*)(data + off);
    float s = blk_sum(v.x + v.y + v.z + v.w, red, tid);
    float mean = s * (1.0f / 1024.0f);
    float d0 = v.x - mean, d1 = v.y - mean, d2 = v.z - mean, d3 = v.w - mean;
    float s2 = blk_sum(d0*d0 + d1*d1 + d2*d2 + d3*d3, red, tid);
    float rstd = rsqrtf(s2 * (1.0f / 1024.0f) + EPS_F);
    float4 gr = *(const float4*)(g  + tid * 4);
    float4 br = *(const float4*)(bb + tid * 4);
    float4 o;
    o.x = d0 * rstd * gr.x + br.x;
    o.y = d1 * rstd * gr.y + br.y;
    o.z = d2 * rstd * gr.z + br.z;
    o.w = d3 * rstd * gr.w + br.w;
    *(float4*)(data + off) = o;
}

// ---------------- transpose+convert: fp32 [1024][1024] -> bf16 T -----------
__global__ __launch_bounds__(256) void transpose_cvt(
    const float* __restrict__ in, unsigned short* __restrict__ outp) {
    __shared__ unsigned short tile[32][33];
    int tid = threadIdx.x;
    int tx = tid & 31, ty = tid >> 5;          // 32 x 8
    int bx = blockIdx.x * 32, by = blockIdx.y * 32;
    #pragma unroll
    for (int r = 0; r < 32; r += 8)
        tile[ty + r][tx] = f2bf(in[(size_t)(by + ty + r) * 1024 + bx + tx]);
    __syncthreads();
    #pragma unroll
    for (int r = 0; r < 32; r += 8)
        outp[(size_t)(bx + ty + r) * 1024 + by + tx] = tile[tx][ty + r];
}

// ---------------- bf16 1024x1024 transpose ---------------------------------
__global__ __launch_bounds__(256) void transpose1024(
    const unsigned short* __restrict__ in, unsigned short* __restrict__ outp) {
    __shared__ unsigned short tile[32][33];
    int tid = threadIdx.x;
    int tx = tid & 31, ty = tid >> 5;
    int bx = blockIdx.x * 32, by = blockIdx.y * 32;
    #pragma unroll
    for (int r = 0; r < 32; r += 8)
        tile[ty + r][tx] = in[(size_t)(by + ty + r) * 1024 + bx + tx];
    __syncthreads();
    #pragma unroll
    for (int r = 0; r < 32; r += 8)
        outp[(size_t)(bx + ty + r) * 1024 + by + tx] = tile[tx][ty + r];
}

// ---------------- fused transpose + LN1: tokens -> X16 (MFMA-tiled) --------
// X16[b][sT][nT][nl][sl]: 16x16 tile (s-contiguous rows of 16), 512B/tile.
// element (b,s,n) at b*4194304 + ((s>>4)*64 + (n>>4))*256 + (n&15)*16 + (s&15)
__global__ __launch_bounds__(256) void transln16_kernel(
    const float* __restrict__ tok, const float* __restrict__ mu,
    const float* __restrict__ rs, const float* __restrict__ g,
    const float* __restrict__ bb, unsigned short* __restrict__ X16) {
    __shared__ unsigned short Lt[32][36];   // [n_local][s_local], pad 36 for 8B align
    int tid = threadIdx.x;
    int tx = tid & 31, ty = tid >> 5;      // 32 x 8
    int s0 = blockIdx.x * 32;              // seq within batch
    int n0 = blockIdx.y * 32;              // feature
    int b  = blockIdx.z;
    float gv = g[n0 + tx], bv = bb[n0 + tx];
    #pragma unroll
    for (int r = 0; r < 32; r += 8) {
        int grow = (b << 12) + s0 + ty + r;
        float v = tok[(size_t)grow * 1024 + n0 + tx];
        Lt[tx][ty + r] = f2bf((v - mu[grow]) * rs[grow] * gv + bv);
    }
    __syncthreads();
    int tt  = tid >> 6;                    // wave -> one 16x16 tile
    int sTl = tt >> 1, nTl = tt & 1;
    int idx = tid & 63;
    int nl  = idx >> 2, so4 = (idx & 3) << 2;   // 4 s-elems = 8B per thread
    uint2 v = *(const uint2*)&Lt[nTl * 16 + nl][sTl * 16 + so4];
    size_t off = (size_t)b * 4194304 +
        (((size_t)(((s0 >> 4) + sTl) * 64 + (n0 >> 4) + nTl)) << 8) +
        (nl << 4) + so4;
    *(uint2*)(X16 + off) = v;
}

// ---------------- small GEMM: Wfused = bf16(Wv @ Wo) -----------------------
__global__ __launch_bounds__(256) void gemm_small(
    const float* __restrict__ A32, const float* __restrict__ W32,
    unsigned short* __restrict__ C16) {
    const int K = 1024, N = 1024;
    __shared__ __align__(16) unsigned short As[64][40];
    __shared__ __align__(16) unsigned short Bs[64][40];
    int tid  = threadIdx.x;
    int lane = tid & 63, wv = tid >> 6;
    int lm   = lane & 15, quad = lane >> 4;
    int m0 = blockIdx.y * 64, n0 = blockIdx.x * 64;
    int srow = tid >> 2, scg = tid & 3;
    int bk   = tid >> 3, bn  = (tid & 7) * 8;

    f32x4 acc[4] = {};
    for (int k0 = 0; k0 < K; k0 += 32) {
        const float* ap = A32 + (size_t)(m0 + srow) * K + k0 + scg * 8;
        float4 p = *(const float4*)(ap);
        float4 q = *(const float4*)(ap + 4);
        union { uint4 u; unsigned short s[8]; } w;
        w.s[0]=f2bf(p.x); w.s[1]=f2bf(p.y); w.s[2]=f2bf(p.z); w.s[3]=f2bf(p.w);
        w.s[4]=f2bf(q.x); w.s[5]=f2bf(q.y); w.s[6]=f2bf(q.z); w.s[7]=f2bf(q.w);
        *(uint4*)&As[srow][scg * 8] = w.u;

        const float* wp = W32 + (size_t)(k0 + bk) * N + n0 + bn;
        float4 a = *(const float4*)wp, b = *(const float4*)(wp + 4);
        float wvv[8] = {a.x,a.y,a.z,a.w,b.x,b.y,b.z,b.w};
        #pragma unroll
        for (int e = 0; e < 8; ++e) Bs[bn + e][bk] = f2bf(wvv[e]);
        __syncthreads();
        bf16x8 af = *(const bf16x8*)&As[wv * 16 + lm][quad * 8];
        #pragma unroll
        for (int t = 0; t < 4; ++t) {
            bf16x8 bfr = *(const bf16x8*)&Bs[t * 16 + lm][quad * 8];
            acc[t] = __builtin_amdgcn_mfma_f32_16x16x32_bf16(af, bfr, acc[t], 0, 0, 0);
        }
        __syncthreads();
    }
    #pragma unroll
    for (int t = 0; t < 4; ++t) {
        int col = n0 + t * 16 + lm;
        #pragma unroll
        for (int r = 0; r < 4; ++r) {
            int row = m0 + wv * 16 + quad * 4 + r;
            C16[(size_t)row * N + col] = f2bf(acc[t][r]);
        }
    }
}

// ---------------- m97-style 128x128 GEMM: C = A[bf16] @ BT[bf16]^T ---------
// (round-4 version: single-buffer; dbuf experiment regressed)
template <bool EPI>
__global__ __launch_bounds__(256) void gemm128(
    const unsigned short* __restrict__ A, const unsigned short* __restrict__ BT,
    unsigned short* __restrict__ C16, float* __restrict__ Cres,
    const float* __restrict__ tok) {
    const int K = 1024, N = 1024;
    __shared__ __align__(16) unsigned short As[4096];  // 4 octets x 128 rows x 8
    __shared__ __align__(16) unsigned short Bs[4096];
    int tid = threadIdx.x, lane = tid & 63, wv = tid >> 6;
    int lm = lane & 15, quad = lane >> 4;
    int wr = wv >> 1, wc = wv & 1;
    // XCD swizzle (dispatch order: x fastest). 1024 = 8*128, bijective.
    int flat = blockIdx.y * 8 + blockIdx.x;
    int logical = ((flat & 7) << 7) | (flat >> 3);
    int m0 = (logical >> 3) * 128, n0 = (logical & 7) * 128;

    f32x4 acc[4][4] = {};

    const unsigned short* ga0 = A  + (size_t)(m0 + lane) * K + wv * 8;
    const unsigned short* ga1 = A  + (size_t)(m0 + 64 + lane) * K + wv * 8;
    const unsigned short* gb0 = BT + (size_t)(n0 + lane) * K + wv * 8;
    const unsigned short* gb1 = BT + (size_t)(n0 + 64 + lane) * K + wv * 8;
    unsigned short* la0 = &As[wv * 1024 + lane * 8];
    unsigned short* la1 = &As[wv * 1024 + 512 + lane * 8];
    unsigned short* lb0 = &Bs[wv * 1024 + lane * 8];
    unsigned short* lb1 = &Bs[wv * 1024 + 512 + lane * 8];

    for (int k0 = 0; k0 < K; k0 += 32) {
        gld_lds16(ga0 + k0, la0);
        gld_lds16(ga1 + k0, la1);
        gld_lds16(gb0 + k0, lb0);
        gld_lds16(gb1 + k0, lb1);
        __syncthreads();
        bf16x8 af[4], bfr[4];
        #pragma unroll
        for (int t = 0; t < 4; ++t) {
            af[t]  = *(const bf16x8*)&As[quad * 1024 + (wr * 64 + t * 16 + lm) * 8];
            bfr[t] = *(const bf16x8*)&Bs[quad * 1024 + (wc * 64 + t * 16 + lm) * 8];
        }
        #pragma unroll
        for (int mt = 0; mt < 4; ++mt)
            #pragma unroll
            for (int nt = 0; nt < 4; ++nt)
                acc[mt][nt] = __builtin_amdgcn_mfma_f32_16x16x32_bf16(
                    af[mt], bfr[nt], acc[mt][nt], 0, 0, 0);
        __syncthreads();
    }
    #pragma unroll
    for (int mt = 0; mt < 4; ++mt) {
        #pragma unroll
        for (int nt = 0; nt < 4; ++nt) {
            int col = n0 + wc * 64 + nt * 16 + lm;
            #pragma unroll
            for (int r = 0; r < 4; ++r) {
                int row = m0 + wr * 64 + mt * 16 + quad * 4 + r;
                size_t idx = (size_t)row * N + col;
                if (EPI) Cres[idx] = tok[idx] + 0.1f * acc[mt][nt][r];
                else     C16[idx]  = f2bf(acc[mt][nt][r]);
            }
        }
    }
}

// ---------------- MFMA sparse attention: 16 queries per block --------------
// Tiles (all 16-aligned, distinct): window [max(0,i0-256)..i0], strided
// i0-128t (t>=3, >=16), global tile 0 (if not already in window).
// Per-element mask applied when writing scores.  P kept bf16 in LDS.
// PV uses X16 tiled layout (16 lines/instr, full-line use).
// Swizzle: two levels.
//  XCD level (frozen, round 3): XCD 2b+0 <- batch b tiles [0,64)u[192,256),
//  XCD 2b+1 <- batch b tiles [64,192). Equal XCD work within 2%.
//  CU level (round 8): slot->CU assumed ROUND-ROBIN (sl&31 = CU; r7 falsified
//  sequential fill). CU g's 4 blocks (j=sl>>5) get constant work-sum tiles:
//  ptyp1 -> {64+g,191-g,96+g,159-g}, ptyp0 -> {g,63-g,192+g,255-g} (sum 510).
//  Each 32-slot span is a 32-consecutive-tile run -> L2 locality preserved.
// NOTE: NO min-occupancy launch_bounds — (256,4) capped VGPR and spilled
// oacc[16] to scratch. Plain (256) compiles to VGPR 128, zero spill.
#define NT_MAX 48
#define SCROW  776    // 48*16 + 8 pad (elems)
__global__ __launch_bounds__(256) void attn16_kernel(
    const unsigned short* __restrict__ Q, const unsigned short* __restrict__ K,
    const unsigned short* __restrict__ XT, unsigned short* __restrict__ Ao) {
    __shared__ __align__(16) unsigned short Ps[16 * SCROW];
    int tid = threadIdx.x, lane = tid & 63, wv = tid >> 6;
    int lm = lane & 15, quad = lane >> 4;
    // two-level balanced swizzle (bijective over 1024 blocks)
    int bxr = blockIdx.x;
    int xcd = bxr & 7;
    int sl  = bxr >> 3;                  // 0..127 slot within XCD
    int batch = xcd >> 1;
    int ptyp  = xcd & 1;
    int g = sl & 31, j = sl >> 5;        // CU 0..31 (round-robin), seq 0..3
    int t;
    if (ptyp) t = (j == 0) ? 64 + g : (j == 1) ? 191 - g
                 : (j == 2) ? 96 + g : 159 - g;
    else      t = (j == 0) ? g       : (j == 1) ? 63 - g
                 : (j == 2) ? 192 + g : 255 - g;
    int bx = batch * 256 + t;
    int b  = bx >> 8;
    int i0 = (bx & 255) << 4;
    int rowbase = (b << 12) + i0;
    // tile bookkeeping (uniform)
    int wlo = i0 - 256; if (wlo < 0) wlo = 0;
    int nwin = ((i0 - wlo) >> 4) + 1;
    int tmax = (i0 - 16) / 128;              // trunc; i0=0 -> 0
    int nstr = tmax - 2; if (nstr < 0) nstr = 0;
    int nglob = (wlo > 0) ? 1 : 0;
    int ntiles = nwin + nstr + nglob;
    int ntp = (ntiles + 3) & ~3;

    // per-lane Q row pointer (a-frag source; row = rowbase + lm)
    const unsigned short* Qg = Q + (size_t)(rowbase + lm) * 1024 + quad * 8;

    // ---- phase 1: score tiles (QK^T), masked write to Ps ----
    const unsigned short* Kbp = K + (((size_t)b << 12) << 10);
    for (int tg = wv * 4; tg < ntp; tg += 16) {
        f32x4 acc[4] = {};
        int tb[4];
        #pragma unroll
        for (int c = 0; c < 4; ++c) {
            int t2 = tg + c, base = 0;
            if (t2 < nwin) base = wlo + (t2 << 4);
            else if (t2 - nwin < nstr) base = i0 - 128 * (3 + (t2 - nwin));
            tb[c] = base;                     // global / padded -> 0
        }
        for (int k0 = 0; k0 < 1024; k0 += 32) {
            bf16x8 a = *(const bf16x8*)(Qg + k0);
            #pragma unroll
            for (int c = 0; c < 4; ++c) {
                bf16x8 bb = *(const bf16x8*)(Kbp +
                    (size_t)(tb[c] + lm) * 1024 + k0 + quad * 8);
                acc[c] = __builtin_amdgcn_mfma_f32_16x16x32_bf16(a, bb, acc[c], 0, 0, 0);
            }
        }
        #pragma unroll
        for (int c = 0; c < 4; ++c) {
            int t2 = tg + c;
            int j2 = tb[c] + lm;
            bool pad = (t2 >= ntiles);
            #pragma unroll
            for (int r = 0; r < 4; ++r) {
                int i = i0 + quad * 4 + r;
                int diff = i - j2;
                bool ok = !pad && (j2 <= i) &&
                          (diff < 256 || (diff & 127) == 0 || j2 < 16);
                Ps[(quad * 4 + r) * SCROW + (t2 << 4) + lm] =
                    f2bf(ok ? acc[c][r] : -1e30f);
            }
        }
    }
    __syncthreads();

    // ---- phase 2: softmax on rows wv*4 .. wv*4+3 ----
    int ncol = ntp << 4;
    for (int q = wv * 4; q < wv * 4 + 4; ++q) {
        unsigned short* row = &Ps[q * SCROW];
        float mx = -1e30f;
        for (int c = lane; c < ncol; c += 64) mx = fmaxf(mx, b2f(row[c]));
        #pragma unroll
        for (int m = 32; m >= 1; m >>= 1) mx = fmaxf(mx, __shfl_xor(mx, m, 64));
        float sm = 0.f;
        for (int c = lane; c < ncol; c += 64)
            sm += __expf(SCALE_F * (b2f(row[c]) - mx));
        #pragma unroll
        for (int m = 32; m >= 1; m >>= 1) sm += __shfl_xor(sm, m, 64);
        float inv = 1.0f / sm;
        for (int c = lane; c < ncol; c += 64)
            row[c] = f2bf(__expf(SCALE_F * (b2f(row[c]) - mx)) * inv);
    }
    __syncthreads();

    // ---- phase 3: O = P @ X16  (wave owns 256 cols = n-tiles nT0..nT0+15) --
    int n0w = wv * 256;
    int nT0 = wv << 4;
    const unsigned short* Xb = XT + (size_t)b * 4194304;
    int octet = quad & 1, tsel = quad >> 1;
    f32x4 oacc[16] = {};
    int nch = ntp >> 1;
    for (int c = 0; c < nch; ++c) {
        int t0 = 2 * c, t1 = 2 * c + 1;
        int b0 = (t0 < nwin) ? wlo + (t0 << 4)
               : ((t0 - nwin < nstr) ? i0 - 128 * (3 + t0 - nwin) : 0);
        int b1 = (t1 < nwin) ? wlo + (t1 << 4)
               : ((t1 - nwin < nstr) ? i0 - 128 * (3 + t1 - nwin) : 0);
        bf16x8 a = *(const bf16x8*)&Ps[lm * SCROW + (c << 5) + quad * 8];
        int sT = (tsel ? b1 : b0) >> 4;
        const unsigned short* xp = Xb + (((size_t)(sT * 64 + nT0)) << 8)
                                      + (lm << 4) + (octet << 3);
        #pragma unroll
        for (int nt = 0; nt < 16; ++nt) {
            bf16x8 bb2 = *(const bf16x8*)(xp + (nt << 8));
            oacc[nt] = __builtin_amdgcn_mfma_f32_16x16x32_bf16(a, bb2, oacc[nt], 0, 0, 0);
        }
    }
    #pragma unroll
    for (int nt = 0; nt < 16; ++nt) {
        int col = n0w + nt * 16 + lm;
        #pragma unroll
        for (int r = 0; r < 4; ++r) {
            int row = rowbase + quad * 4 + r;
            Ao[(size_t)row * 1024 + col] = f2bf(oacc[nt][r]);
        }
    }
}

// ---------------------------------------------------------------------------
extern "C" void kernel_launch(void* const* d_in, const int* in_sizes, int n_in,
                              void* d_out, int out_size, void* d_ws, size_t ws_size,
                              hipStream_t stream) {
    const float* tokens = (const float*)d_in[0];
    const float* Wq = (const float*)d_in[1];
    const float* Wk = (const float*)d_in[2];
    const float* Wv = (const float*)d_in[3];
    const float* Wo = (const float*)d_in[4];
    const float* g1 = (const float*)d_in[5];
    const float* b1 = (const float*)d_in[6];
    const float* g2 = (const float*)d_in[7];
    const float* b2 = (const float*)d_in[8];
    float* out = (float*)d_out;
    char* ws = (char*)d_ws;

    // ws (41MB):
    //   mu @0 (64KB), rs @64KB, WqT @1MB, WkT @3MB, Wfused @5MB, WfT @7MB,
    //   Q bf16 @9MB..41MB  -> attnX written in place
    // d_out (64MB fp32) as staging:
    //   xb bf16 @[0:32MB)  -> overwritten by X16 after Q/K gemms
    //   K  bf16 @[32:64MB)
    // then out-gemm overwrites all of d_out with fp32 residual; LN2 in place.
    const size_t MB = 1048576;
    float* mu = (float*)(ws);
    float* rs = (float*)(ws + 65536);
    unsigned short* WqT    = (unsigned short*)(ws + 1 * MB);
    unsigned short* WkT    = (unsigned short*)(ws + 3 * MB);
    unsigned short* Wfused = (unsigned short*)(ws + 5 * MB);
    unsigned short* WfT    = (unsigned short*)(ws + 7 * MB);
    unsigned short* Qb     = (unsigned short*)(ws + 9 * MB);
    unsigned short* xb     = (unsigned short*)d_out;
    unsigned short* X16    = (unsigned short*)d_out;   // overwrites xb later
    unsigned short* Kb     = (unsigned short*)d_out + 16777216;
    unsigned short* attnX  = Qb;

    dim3 b256(256);
    const int ROWS = 4 * S_LEN;           // 16384
    dim3 tg(32, 32);
    dim3 gsmall(16, 16);
    dim3 g128(8, 128);                    // N/128 x M/128
    dim3 gtl(128, 32, 4);                 // transLN16: s-tiles x n-tiles x batch

    // 1. LN1: stats + xb (row-major)
    ln_full_kernel<<<ROWS, b256, 0, stream>>>(tokens, mu, rs, g1, b1, xb);
    // 2. weight prep
    transpose_cvt<<<tg, b256, 0, stream>>>(Wq, WqT);
    transpose_cvt<<<tg, b256, 0, stream>>>(Wk, WkT);
    gemm_small<<<gsmall, b256, 0, stream>>>(Wv, Wo, Wfused);
    transpose1024<<<tg, b256, 0, stream>>>(Wfused, WfT);
    // 3. Q = xb@Wq, K = xb@Wk
    gemm128<false><<<g128, b256, 0, stream>>>(xb, WqT, Qb, nullptr, nullptr);
    gemm128<false><<<g128, b256, 0, stream>>>(xb, WkT, Kb, nullptr, nullptr);
    // 4. X16 = tiled(LN1(tokens)) per batch (overwrites xb; reads tokens)
    transln16_kernel<<<gtl, b256, 0, stream>>>(tokens, mu, rs, g1, b1, X16);
    // 5. MFMA sparse attention (attnX over Q)
    attn16_kernel<<<1024, b256, 0, stream>>>(Qb, Kb, X16, attnX);
    // 6. out = tokens + 0.1*(attnX @ Wfused)
    gemm128<true><<<g128, b256, 0, stream>>>(attnX, WfT, nullptr, out, tokens);
    // 7. LN2 in place
    ln2_inplace_kernel<<<ROWS, b256, 0, stream>>>(out, g2, b2);
}

// Round 9
// 645.232 us; speedup vs baseline: 1.1469x; 1.0300x over previous
//
#include <hip/hip_runtime.h>

// Problem constants
#define S_LEN   4096
#define D_DIM   1024
#define WIN_    256
#define STRIDE_ 128
#define GLOB_   16
#define SCALE_F 0.03125f   // 1/sqrt(1024)
#define EPS_F   1e-5f

typedef __bf16 bf16x8 __attribute__((ext_vector_type(8)));
typedef float  f32x4  __attribute__((ext_vector_type(4)));

__device__ __forceinline__ float b2f(unsigned short u) {
    union { unsigned int i; float f; } c; c.i = ((unsigned int)u) << 16; return c.f;
}
__device__ __forceinline__ unsigned short f2bf(float f) {
    union { float f; unsigned int i; } c; c.f = f;
    unsigned int u = c.i;
    u += 0x7fffu + ((u >> 16) & 1u);   // round-to-nearest-even
    return (unsigned short)(u >> 16);
}

// async global->LDS, 16B per lane (dest = wave-uniform base + lane*16)
__device__ __forceinline__ void gld_lds16(const void* g, void* l) {
    __builtin_amdgcn_global_load_lds(
        (const __attribute__((address_space(1))) unsigned int*)g,
        (__attribute__((address_space(3))) unsigned int*)l, 16, 0, 0);
}

// ---------------- block reduction helper (256 threads = 4 waves) -----------
__device__ __forceinline__ float blk_sum(float v, float* red, int tid) {
    int lane = tid & 63, wv = tid >> 6;
    #pragma unroll
    for (int m = 32; m >= 1; m >>= 1) v += __shfl_xor(v, m, 64);
    __syncthreads();
    if (lane == 0) red[wv] = v;
    __syncthreads();
    return red[0] + red[1] + red[2] + red[3];
}

// ---------------- LN1 full: mu/rs + xb = bf16(LN(tok)*g1+b1) ---------------
__global__ __launch_bounds__(256) void ln_full_kernel(
    const float* __restrict__ in, float* __restrict__ mu, float* __restrict__ rs,
    const float* __restrict__ g, const float* __restrict__ bb,
    unsigned short* __restrict__ xb) {
    __shared__ float red[4];
    int row = blockIdx.x, tid = threadIdx.x;
    size_t off = (size_t)row * D_DIM + tid * 4;
    float4 r = *(const float4*)(in + off);
    float s = blk_sum(r.x + r.y + r.z + r.w, red, tid);
    float mean = s * (1.0f / 1024.0f);
    float d0 = r.x - mean, d1 = r.y - mean, d2 = r.z - mean, d3 = r.w - mean;
    float s2 = blk_sum(d0*d0 + d1*d1 + d2*d2 + d3*d3, red, tid);
    float rstd = rsqrtf(s2 * (1.0f / 1024.0f) + EPS_F);
    if (tid == 0) { mu[row] = mean; rs[row] = rstd; }
    float4 gr = *(const float4*)(g  + tid * 4);
    float4 br = *(const float4*)(bb + tid * 4);
    ushort4 o;
    o.x = f2bf(d0 * rstd * gr.x + br.x);
    o.y = f2bf(d1 * rstd * gr.y + br.y);
    o.z = f2bf(d2 * rstd * gr.z + br.z);
    o.w = f2bf(d3 * rstd * gr.w + br.w);
    *(ushort4*)(xb + off) = o;
}

// ---------------- LN2 in place (fp32, block-local rows) --------------------
__global__ __launch_bounds__(256) void ln2_inplace_kernel(
    float* __restrict__ data, const float* __restrict__ g,
    const float* __restrict__ bb) {
    __shared__ float red[4];
    int row = blockIdx.x, tid = threadIdx.x;
    size_t off = (size_t)row * D_DIM + tid * 4;
    float4 v = *(const float4*)(data + off);
    float s = blk_sum(v.x + v.y + v.z + v.w, red, tid);
    float mean = s * (1.0f / 1024.0f);
    float d0 = v.x - mean, d1 = v.y - mean, d2 = v.z - mean, d3 = v.w - mean;
    float s2 = blk_sum(d0*d0 + d1*d1 + d2*d2 + d3*d3, red, tid);
    float rstd = rsqrtf(s2 * (1.0f / 1024.0f) + EPS_F);
    float4 gr = *(const float4*)(g  + tid * 4);
    float4 br = *(const float4*)(bb + tid * 4);
    float4 o;
    o.x = d0 * rstd * gr.x + br.x;
    o.y = d1 * rstd * gr.y + br.y;
    o.z = d2 * rstd * gr.z + br.z;
    o.w = d3 * rstd * gr.w + br.w;
    *(float4*)(data + off) = o;
}

// ---------------- transpose+convert: fp32 [1024][1024] -> bf16 T -----------
__global__ __launch_bounds__(256) void transpose_cvt(
    const float* __restrict__ in, unsigned short* __restrict__ outp) {
    __shared__ unsigned short tile[32][33];
    int tid = threadIdx.x;
    int tx = tid & 31, ty = tid >> 5;          // 32 x 8
    int bx = blockIdx.x * 32, by = blockIdx.y * 32;
    #pragma unroll
    for (int r = 0; r < 32; r += 8)
        tile[ty + r][tx] = f2bf(in[(size_t)(by + ty + r) * 1024 + bx + tx]);
    __syncthreads();
    #pragma unroll
    for (int r = 0; r < 32; r += 8)
        outp[(size_t)(bx + ty + r) * 1024 + by + tx] = tile[tx][ty + r];
}

// ---------------- bf16 1024x1024 transpose ---------------------------------
__global__ __launch_bounds__(256) void transpose1024(
    const unsigned short* __restrict__ in, unsigned short* __restrict__ outp) {
    __shared__ unsigned short tile[32][33];
    int tid = threadIdx.x;
    int tx = tid & 31, ty = tid >> 5;
    int bx = blockIdx.x * 32, by = blockIdx.y * 32;
    #pragma unroll
    for (int r = 0; r < 32; r += 8)
        tile[ty + r][tx] = in[(size_t)(by + ty + r) * 1024 + bx + tx];
    __syncthreads();
    #pragma unroll
    for (int r = 0; r < 32; r += 8)
        outp[(size_t)(bx + ty + r) * 1024 + by + tx] = tile[tx][ty + r];
}

// ---------------- fused transpose + LN1: tokens -> X16 (MFMA-tiled) --------
// X16[b][sT][nT][nl][sl]: 16x16 tile (s-contiguous rows of 16), 512B/tile.
// element (b,s,n) at b*4194304 + ((s>>4)*64 + (n>>4))*256 + (n&15)*16 + (s&15)
__global__ __launch_bounds__(256) void transln16_kernel(
    const float* __restrict__ tok, const float* __restrict__ mu,
    const float* __restrict__ rs, const float* __restrict__ g,
    const float* __restrict__ bb, unsigned short* __restrict__ X16) {
    __shared__ unsigned short Lt[32][36];   // [n_local][s_local], pad 36 for 8B align
    int tid = threadIdx.x;
    int tx = tid & 31, ty = tid >> 5;      // 32 x 8
    int s0 = blockIdx.x * 32;              // seq within batch
    int n0 = blockIdx.y * 32;              // feature
    int b  = blockIdx.z;
    float gv = g[n0 + tx], bv = bb[n0 + tx];
    #pragma unroll
    for (int r = 0; r < 32; r += 8) {
        int grow = (b << 12) + s0 + ty + r;
        float v = tok[(size_t)grow * 1024 + n0 + tx];
        Lt[tx][ty + r] = f2bf((v - mu[grow]) * rs[grow] * gv + bv);
    }
    __syncthreads();
    int tt  = tid >> 6;                    // wave -> one 16x16 tile
    int sTl = tt >> 1, nTl = tt & 1;
    int idx = tid & 63;
    int nl  = idx >> 2, so4 = (idx & 3) << 2;   // 4 s-elems = 8B per thread
    uint2 v = *(const uint2*)&Lt[nTl * 16 + nl][sTl * 16 + so4];
    size_t off = (size_t)b * 4194304 +
        (((size_t)(((s0 >> 4) + sTl) * 64 + (n0 >> 4) + nTl)) << 8) +
        (nl << 4) + so4;
    *(uint2*)(X16 + off) = v;
}

// ---------------- small GEMM: Wfused = bf16(Wv @ Wo) -----------------------
__global__ __launch_bounds__(256) void gemm_small(
    const float* __restrict__ A32, const float* __restrict__ W32,
    unsigned short* __restrict__ C16) {
    const int K = 1024, N = 1024;
    __shared__ __align__(16) unsigned short As[64][40];
    __shared__ __align__(16) unsigned short Bs[64][40];
    int tid  = threadIdx.x;
    int lane = tid & 63, wv = tid >> 6;
    int lm   = lane & 15, quad = lane >> 4;
    int m0 = blockIdx.y * 64, n0 = blockIdx.x * 64;
    int srow = tid >> 2, scg = tid & 3;
    int bk   = tid >> 3, bn  = (tid & 7) * 8;

    f32x4 acc[4] = {};
    for (int k0 = 0; k0 < K; k0 += 32) {
        const float* ap = A32 + (size_t)(m0 + srow) * K + k0 + scg * 8;
        float4 p = *(const float4*)(ap);
        float4 q = *(const float4*)(ap + 4);
        union { uint4 u; unsigned short s[8]; } w;
        w.s[0]=f2bf(p.x); w.s[1]=f2bf(p.y); w.s[2]=f2bf(p.z); w.s[3]=f2bf(p.w);
        w.s[4]=f2bf(q.x); w.s[5]=f2bf(q.y); w.s[6]=f2bf(q.z); w.s[7]=f2bf(q.w);
        *(uint4*)&As[srow][scg * 8] = w.u;

        const float* wp = W32 + (size_t)(k0 + bk) * N + n0 + bn;
        float4 a = *(const float4*)wp, b = *(const float4*)(wp + 4);
        float wvv[8] = {a.x,a.y,a.z,a.w,b.x,b.y,b.z,b.w};
        #pragma unroll
        for (int e = 0; e < 8; ++e) Bs[bn + e][bk] = f2bf(wvv[e]);
        __syncthreads();
        bf16x8 af = *(const bf16x8*)&As[wv * 16 + lm][quad * 8];
        #pragma unroll
        for (int t = 0; t < 4; ++t) {
            bf16x8 bfr = *(const bf16x8*)&Bs[t * 16 + lm][quad * 8];
            acc[t] = __builtin_amdgcn_mfma_f32_16x16x32_bf16(af, bfr, acc[t], 0, 0, 0);
        }
        __syncthreads();
    }
    #pragma unroll
    for (int t = 0; t < 4; ++t) {
        int col = n0 + t * 16 + lm;
        #pragma unroll
        for (int r = 0; r < 4; ++r) {
            int row = m0 + wv * 16 + quad * 4 + r;
            C16[(size_t)row * N + col] = f2bf(acc[t][r]);
        }
    }
}

// ---------------- m97-style 128x128 GEMM (EPI residual variant) ------------
template <bool EPI>
__global__ __launch_bounds__(256) void gemm128(
    const unsigned short* __restrict__ A, const unsigned short* __restrict__ BT,
    unsigned short* __restrict__ C16, float* __restrict__ Cres,
    const float* __restrict__ tok) {
    const int K = 1024, N = 1024;
    __shared__ __align__(16) unsigned short As[4096];  // 4 octets x 128 rows x 8
    __shared__ __align__(16) unsigned short Bs[4096];
    int tid = threadIdx.x, lane = tid & 63, wv = tid >> 6;
    int lm = lane & 15, quad = lane >> 4;
    int wr = wv >> 1, wc = wv & 1;
    // XCD swizzle (dispatch order: x fastest). 1024 = 8*128, bijective.
    int flat = blockIdx.y * 8 + blockIdx.x;
    int logical = ((flat & 7) << 7) | (flat >> 3);
    int m0 = (logical >> 3) * 128, n0 = (logical & 7) * 128;

    f32x4 acc[4][4] = {};

    const unsigned short* ga0 = A  + (size_t)(m0 + lane) * K + wv * 8;
    const unsigned short* ga1 = A  + (size_t)(m0 + 64 + lane) * K + wv * 8;
    const unsigned short* gb0 = BT + (size_t)(n0 + lane) * K + wv * 8;
    const unsigned short* gb1 = BT + (size_t)(n0 + 64 + lane) * K + wv * 8;
    unsigned short* la0 = &As[wv * 1024 + lane * 8];
    unsigned short* la1 = &As[wv * 1024 + 512 + lane * 8];
    unsigned short* lb0 = &Bs[wv * 1024 + lane * 8];
    unsigned short* lb1 = &Bs[wv * 1024 + 512 + lane * 8];

    for (int k0 = 0; k0 < K; k0 += 32) {
        gld_lds16(ga0 + k0, la0);
        gld_lds16(ga1 + k0, la1);
        gld_lds16(gb0 + k0, lb0);
        gld_lds16(gb1 + k0, lb1);
        __syncthreads();
        bf16x8 af[4], bfr[4];
        #pragma unroll
        for (int t = 0; t < 4; ++t) {
            af[t]  = *(const bf16x8*)&As[quad * 1024 + (wr * 64 + t * 16 + lm) * 8];
            bfr[t] = *(const bf16x8*)&Bs[quad * 1024 + (wc * 64 + t * 16 + lm) * 8];
        }
        #pragma unroll
        for (int mt = 0; mt < 4; ++mt)
            #pragma unroll
            for (int nt = 0; nt < 4; ++nt)
                acc[mt][nt] = __builtin_amdgcn_mfma_f32_16x16x32_bf16(
                    af[mt], bfr[nt], acc[mt][nt], 0, 0, 0);
        __syncthreads();
    }
    #pragma unroll
    for (int mt = 0; mt < 4; ++mt) {
        #pragma unroll
        for (int nt = 0; nt < 4; ++nt) {
            int col = n0 + wc * 64 + nt * 16 + lm;
            #pragma unroll
            for (int r = 0; r < 4; ++r) {
                int row = m0 + wr * 64 + mt * 16 + quad * 4 + r;
                size_t idx = (size_t)row * N + col;
                if (EPI) Cres[idx] = tok[idx] + 0.1f * acc[mt][nt][r];
                else     C16[idx]  = f2bf(acc[mt][nt][r]);
            }
        }
    }
}

// ------- merged Q/K GEMM: [Qb|Kb] = xb @ [WqT;WkT]^T  (N=2048) -------------
// WqT (ws+1MB) and WkT (ws+3MB) are contiguous -> single BT[2048][1024].
// One A-stream instead of two; col<1024 -> Qb, else Kb (wave-uniform branch).
// XCD swizzle: 2048 = 8*256 bijective; each XCD gets 16 consecutive M-tiles
// x 16 N-tiles.
__global__ __launch_bounds__(256) void gemm128qk(
    const unsigned short* __restrict__ A, const unsigned short* __restrict__ BT,
    unsigned short* __restrict__ Qb, unsigned short* __restrict__ Kb) {
    const int K = 1024;
    __shared__ __align__(16) unsigned short As[4096];
    __shared__ __align__(16) unsigned short Bs[4096];
    int tid = threadIdx.x, lane = tid & 63, wv = tid >> 6;
    int lm = lane & 15, quad = lane >> 4;
    int wr = wv >> 1, wc = wv & 1;
    int flat = blockIdx.y * 16 + blockIdx.x;
    int logical = ((flat & 7) << 8) | (flat >> 3);
    int m0 = (logical >> 4) * 128, n0 = (logical & 15) * 128;

    f32x4 acc[4][4] = {};

    const unsigned short* ga0 = A  + (size_t)(m0 + lane) * K + wv * 8;
    const unsigned short* ga1 = A  + (size_t)(m0 + 64 + lane) * K + wv * 8;
    const unsigned short* gb0 = BT + (size_t)(n0 + lane) * K + wv * 8;
    const unsigned short* gb1 = BT + (size_t)(n0 + 64 + lane) * K + wv * 8;
    unsigned short* la0 = &As[wv * 1024 + lane * 8];
    unsigned short* la1 = &As[wv * 1024 + 512 + lane * 8];
    unsigned short* lb0 = &Bs[wv * 1024 + lane * 8];
    unsigned short* lb1 = &Bs[wv * 1024 + 512 + lane * 8];

    for (int k0 = 0; k0 < K; k0 += 32) {
        gld_lds16(ga0 + k0, la0);
        gld_lds16(ga1 + k0, la1);
        gld_lds16(gb0 + k0, lb0);
        gld_lds16(gb1 + k0, lb1);
        __syncthreads();
        bf16x8 af[4], bfr[4];
        #pragma unroll
        for (int t = 0; t < 4; ++t) {
            af[t]  = *(const bf16x8*)&As[quad * 1024 + (wr * 64 + t * 16 + lm) * 8];
            bfr[t] = *(const bf16x8*)&Bs[quad * 1024 + (wc * 64 + t * 16 + lm) * 8];
        }
        #pragma unroll
        for (int mt = 0; mt < 4; ++mt)
            #pragma unroll
            for (int nt = 0; nt < 4; ++nt)
                acc[mt][nt] = __builtin_amdgcn_mfma_f32_16x16x32_bf16(
                    af[mt], bfr[nt], acc[mt][nt], 0, 0, 0);
        __syncthreads();
    }
    unsigned short* dst = (n0 < 1024) ? Qb : Kb;
    int nbase = (n0 < 1024) ? n0 : (n0 - 1024);
    #pragma unroll
    for (int mt = 0; mt < 4; ++mt) {
        #pragma unroll
        for (int nt = 0; nt < 4; ++nt) {
            int col = nbase + wc * 64 + nt * 16 + lm;
            #pragma unroll
            for (int r = 0; r < 4; ++r) {
                int row = m0 + wr * 64 + mt * 16 + quad * 4 + r;
                dst[(size_t)row * 1024 + col] = f2bf(acc[mt][nt][r]);
            }
        }
    }
}

// ---------------- MFMA sparse attention: 16 queries per block --------------
// (round-8 code, frozen: 227-229us, occ 20%, VGPR 128. Swizzle: XCD-level
// quarter-pairing + round-robin CU-level sum-510 groups. Per-CU balance
// proven null (r8) but harmless; kept.)
#define NT_MAX 48
#define SCROW  776    // 48*16 + 8 pad (elems)
__global__ __launch_bounds__(256) void attn16_kernel(
    const unsigned short* __restrict__ Q, const unsigned short* __restrict__ K,
    const unsigned short* __restrict__ XT, unsigned short* __restrict__ Ao) {
    __shared__ __align__(16) unsigned short Ps[16 * SCROW];
    int tid = threadIdx.x, lane = tid & 63, wv = tid >> 6;
    int lm = lane & 15, quad = lane >> 4;
    int bxr = blockIdx.x;
    int xcd = bxr & 7;
    int sl  = bxr >> 3;                  // 0..127 slot within XCD
    int batch = xcd >> 1;
    int ptyp  = xcd & 1;
    int g = sl & 31, j = sl >> 5;        // CU 0..31 (round-robin), seq 0..3
    int t;
    if (ptyp) t = (j == 0) ? 64 + g : (j == 1) ? 191 - g
                 : (j == 2) ? 96 + g : 159 - g;
    else      t = (j == 0) ? g       : (j == 1) ? 63 - g
                 : (j == 2) ? 192 + g : 255 - g;
    int bx = batch * 256 + t;
    int b  = bx >> 8;
    int i0 = (bx & 255) << 4;
    int rowbase = (b << 12) + i0;
    int wlo = i0 - 256; if (wlo < 0) wlo = 0;
    int nwin = ((i0 - wlo) >> 4) + 1;
    int tmax = (i0 - 16) / 128;              // trunc; i0=0 -> 0
    int nstr = tmax - 2; if (nstr < 0) nstr = 0;
    int nglob = (wlo > 0) ? 1 : 0;
    int ntiles = nwin + nstr + nglob;
    int ntp = (ntiles + 3) & ~3;

    const unsigned short* Qg = Q + (size_t)(rowbase + lm) * 1024 + quad * 8;

    // ---- phase 1: score tiles (QK^T), masked write to Ps ----
    const unsigned short* Kbp = K + (((size_t)b << 12) << 10);
    for (int tg = wv * 4; tg < ntp; tg += 16) {
        f32x4 acc[4] = {};
        int tb[4];
        #pragma unroll
        for (int c = 0; c < 4; ++c) {
            int t2 = tg + c, base = 0;
            if (t2 < nwin) base = wlo + (t2 << 4);
            else if (t2 - nwin < nstr) base = i0 - 128 * (3 + (t2 - nwin));
            tb[c] = base;                     // global / padded -> 0
        }
        for (int k0 = 0; k0 < 1024; k0 += 32) {
            bf16x8 a = *(const bf16x8*)(Qg + k0);
            #pragma unroll
            for (int c = 0; c < 4; ++c) {
                bf16x8 bb = *(const bf16x8*)(Kbp +
                    (size_t)(tb[c] + lm) * 1024 + k0 + quad * 8);
                acc[c] = __builtin_amdgcn_mfma_f32_16x16x32_bf16(a, bb, acc[c], 0, 0, 0);
            }
        }
        #pragma unroll
        for (int c = 0; c < 4; ++c) {
            int t2 = tg + c;
            int j2 = tb[c] + lm;
            bool pad = (t2 >= ntiles);
            #pragma unroll
            for (int r = 0; r < 4; ++r) {
                int i = i0 + quad * 4 + r;
                int diff = i - j2;
                bool ok = !pad && (j2 <= i) &&
                          (diff < 256 || (diff & 127) == 0 || j2 < 16);
                Ps[(quad * 4 + r) * SCROW + (t2 << 4) + lm] =
                    f2bf(ok ? acc[c][r] : -1e30f);
            }
        }
    }
    __syncthreads();

    // ---- phase 2: softmax on rows wv*4 .. wv*4+3 ----
    int ncol = ntp << 4;
    for (int q = wv * 4; q < wv * 4 + 4; ++q) {
        unsigned short* row = &Ps[q * SCROW];
        float mx = -1e30f;
        for (int c = lane; c < ncol; c += 64) mx = fmaxf(mx, b2f(row[c]));
        #pragma unroll
        for (int m = 32; m >= 1; m >>= 1) mx = fmaxf(mx, __shfl_xor(mx, m, 64));
        float sm = 0.f;
        for (int c = lane; c < ncol; c += 64)
            sm += __expf(SCALE_F * (b2f(row[c]) - mx));
        #pragma unroll
        for (int m = 32; m >= 1; m >>= 1) sm += __shfl_xor(sm, m, 64);
        float inv = 1.0f / sm;
        for (int c = lane; c < ncol; c += 64)
            row[c] = f2bf(__expf(SCALE_F * (b2f(row[c]) - mx)) * inv);
    }
    __syncthreads();

    // ---- phase 3: O = P @ X16  (wave owns 256 cols = n-tiles nT0..nT0+15) --
    int n0w = wv * 256;
    int nT0 = wv << 4;
    const unsigned short* Xb = XT + (size_t)b * 4194304;
    int octet = quad & 1, tsel = quad >> 1;
    f32x4 oacc[16] = {};
    int nch = ntp >> 1;
    for (int c = 0; c < nch; ++c) {
        int t0 = 2 * c, t1 = 2 * c + 1;
        int b0 = (t0 < nwin) ? wlo + (t0 << 4)
               : ((t0 - nwin < nstr) ? i0 - 128 * (3 + t0 - nwin) : 0);
        int b1 = (t1 < nwin) ? wlo + (t1 << 4)
               : ((t1 - nwin < nstr) ? i0 - 128 * (3 + t1 - nwin) : 0);
        bf16x8 a = *(const bf16x8*)&Ps[lm * SCROW + (c << 5) + quad * 8];
        int sT = (tsel ? b1 : b0) >> 4;
        const unsigned short* xp = Xb + (((size_t)(sT * 64 + nT0)) << 8)
                                      + (lm << 4) + (octet << 3);
        #pragma unroll
        for (int nt = 0; nt < 16; ++nt) {
            bf16x8 bb2 = *(const bf16x8*)(xp + (nt << 8));
            oacc[nt] = __builtin_amdgcn_mfma_f32_16x16x32_bf16(a, bb2, oacc[nt], 0, 0, 0);
        }
    }
    #pragma unroll
    for (int nt = 0; nt < 16; ++nt) {
        int col = n0w + nt * 16 + lm;
        #pragma unroll
        for (int r = 0; r < 4; ++r) {
            int row = rowbase + quad * 4 + r;
            Ao[(size_t)row * 1024 + col] = f2bf(oacc[nt][r]);
        }
    }
}

// ---------------------------------------------------------------------------
extern "C" void kernel_launch(void* const* d_in, const int* in_sizes, int n_in,
                              void* d_out, int out_size, void* d_ws, size_t ws_size,
                              hipStream_t stream) {
    const float* tokens = (const float*)d_in[0];
    const float* Wq = (const float*)d_in[1];
    const float* Wk = (const float*)d_in[2];
    const float* Wv = (const float*)d_in[3];
    const float* Wo = (const float*)d_in[4];
    const float* g1 = (const float*)d_in[5];
    const float* b1 = (const float*)d_in[6];
    const float* g2 = (const float*)d_in[7];
    const float* b2 = (const float*)d_in[8];
    float* out = (float*)d_out;
    char* ws = (char*)d_ws;

    // ws (41MB):
    //   mu @0 (64KB), rs @64KB, WqT @1MB, WkT @3MB (contiguous with WqT ->
    //   single [2048][1024] BT for merged QK gemm), Wfused @5MB, WfT @7MB,
    //   Q bf16 @9MB..41MB  -> attnX written in place
    // d_out (64MB fp32) as staging:
    //   xb bf16 @[0:32MB)  -> overwritten by X16 after QK gemm
    //   K  bf16 @[32:64MB)
    // then out-gemm overwrites all of d_out with fp32 residual; LN2 in place.
    const size_t MB = 1048576;
    float* mu = (float*)(ws);
    float* rs = (float*)(ws + 65536);
    unsigned short* WqT    = (unsigned short*)(ws + 1 * MB);
    unsigned short* WkT    = (unsigned short*)(ws + 3 * MB);
    unsigned short* Wfused = (unsigned short*)(ws + 5 * MB);
    unsigned short* WfT    = (unsigned short*)(ws + 7 * MB);
    unsigned short* Qb     = (unsigned short*)(ws + 9 * MB);
    unsigned short* xb     = (unsigned short*)d_out;
    unsigned short* X16    = (unsigned short*)d_out;   // overwrites xb later
    unsigned short* Kb     = (unsigned short*)d_out + 16777216;
    unsigned short* attnX  = Qb;

    dim3 b256(256);
    const int ROWS = 4 * S_LEN;           // 16384
    dim3 tg(32, 32);
    dim3 gsmall(16, 16);
    dim3 g128(8, 128);                    // N/128 x M/128 (out-gemm)
    dim3 gqk(16, 128);                    // merged QK: N=2048
    dim3 gtl(128, 32, 4);                 // transLN16: s-tiles x n-tiles x batch

    // 1. LN1: stats + xb (row-major)
    ln_full_kernel<<<ROWS, b256, 0, stream>>>(tokens, mu, rs, g1, b1, xb);
    // 2. weight prep
    transpose_cvt<<<tg, b256, 0, stream>>>(Wq, WqT);
    transpose_cvt<<<tg, b256, 0, stream>>>(Wk, WkT);
    gemm_small<<<gsmall, b256, 0, stream>>>(Wv, Wo, Wfused);
    transpose1024<<<tg, b256, 0, stream>>>(Wfused, WfT);
    // 3. [Q|K] = xb @ [Wq|Wk]  (merged, one A-stream)
    gemm128qk<<<gqk, b256, 0, stream>>>(xb, WqT, Qb, Kb);
    // 4. X16 = tiled(LN1(tokens)) per batch (overwrites xb; reads tokens)
    transln16_kernel<<<gtl, b256, 0, stream>>>(tokens, mu, rs, g1, b1, X16);
    // 5. MFMA sparse attention (attnX over Q)
    attn16_kernel<<<1024, b256, 0, stream>>>(Qb, Kb, X16, attnX);
    // 6. out = tokens + 0.1*(attnX @ Wfused)
    gemm128<true><<<g128, b256, 0, stream>>>(attnX, WfT, nullptr, out, tokens);
    // 7. LN2 in place
    ln2_inplace_kernel<<<ROWS, b256, 0, stream>>>(out, g2, b2);
}

// Round 10
// 643.096 us; speedup vs baseline: 1.1507x; 1.0033x over previous
//
#include <hip/hip_runtime.h>

// Problem constants
#define S_LEN   4096
#define D_DIM   1024
#define WIN_    256
#define STRIDE_ 128
#define GLOB_   16
#define SCALE_F 0.03125f   // 1/sqrt(1024)
#define EPS_F   1e-5f

typedef __bf16 bf16x8 __attribute__((ext_vector_type(8)));
typedef float  f32x4  __attribute__((ext_vector_type(4)));

__device__ __forceinline__ float b2f(unsigned short u) {
    union { unsigned int i; float f; } c; c.i = ((unsigned int)u) << 16; return c.f;
}
__device__ __forceinline__ unsigned short f2bf(float f) {
    union { float f; unsigned int i; } c; c.f = f;
    unsigned int u = c.i;
    u += 0x7fffu + ((u >> 16) & 1u);   // round-to-nearest-even
    return (unsigned short)(u >> 16);
}

// async global->LDS, 16B per lane (dest = wave-uniform base + lane*16)
__device__ __forceinline__ void gld_lds16(const void* g, void* l) {
    __builtin_amdgcn_global_load_lds(
        (const __attribute__((address_space(1))) unsigned int*)g,
        (__attribute__((address_space(3))) unsigned int*)l, 16, 0, 0);
}

// ---------------- block reduction helper (256 threads = 4 waves) -----------
__device__ __forceinline__ float blk_sum(float v, float* red, int tid) {
    int lane = tid & 63, wv = tid >> 6;
    #pragma unroll
    for (int m = 32; m >= 1; m >>= 1) v += __shfl_xor(v, m, 64);
    __syncthreads();
    if (lane == 0) red[wv] = v;
    __syncthreads();
    return red[0] + red[1] + red[2] + red[3];
}

// ---------------- LN1 full: mu/rs + xb = bf16(LN(tok)*g1+b1) ---------------
__global__ __launch_bounds__(256) void ln_full_kernel(
    const float* __restrict__ in, float* __restrict__ mu, float* __restrict__ rs,
    const float* __restrict__ g, const float* __restrict__ bb,
    unsigned short* __restrict__ xb) {
    __shared__ float red[4];
    int row = blockIdx.x, tid = threadIdx.x;
    size_t off = (size_t)row * D_DIM + tid * 4;
    float4 r = *(const float4*)(in + off);
    float s = blk_sum(r.x + r.y + r.z + r.w, red, tid);
    float mean = s * (1.0f / 1024.0f);
    float d0 = r.x - mean, d1 = r.y - mean, d2 = r.z - mean, d3 = r.w - mean;
    float s2 = blk_sum(d0*d0 + d1*d1 + d2*d2 + d3*d3, red, tid);
    float rstd = rsqrtf(s2 * (1.0f / 1024.0f) + EPS_F);
    if (tid == 0) { mu[row] = mean; rs[row] = rstd; }
    float4 gr = *(const float4*)(g  + tid * 4);
    float4 br = *(const float4*)(bb + tid * 4);
    ushort4 o;
    o.x = f2bf(d0 * rstd * gr.x + br.x);
    o.y = f2bf(d1 * rstd * gr.y + br.y);
    o.z = f2bf(d2 * rstd * gr.z + br.z);
    o.w = f2bf(d3 * rstd * gr.w + br.w);
    *(ushort4*)(xb + off) = o;
}

// ---------------- LN2 in place (fp32, block-local rows) --------------------
__global__ __launch_bounds__(256) void ln2_inplace_kernel(
    float* __restrict__ data, const float* __restrict__ g,
    const float* __restrict__ bb) {
    __shared__ float red[4];
    int row = blockIdx.x, tid = threadIdx.x;
    size_t off = (size_t)row * D_DIM + tid * 4;
    float4 v = *(const float4*)(data + off);
    float s = blk_sum(v.x + v.y + v.z + v.w, red, tid);
    float mean = s * (1.0f / 1024.0f);
    float d0 = v.x - mean, d1 = v.y - mean, d2 = v.z - mean, d3 = v.w - mean;
    float s2 = blk_sum(d0*d0 + d1*d1 + d2*d2 + d3*d3, red, tid);
    float rstd = rsqrtf(s2 * (1.0f / 1024.0f) + EPS_F);
    float4 gr = *(const float4*)(g  + tid * 4);
    float4 br = *(const float4*)(bb + tid * 4);
    float4 o;
    o.x = d0 * rstd * gr.x + br.x;
    o.y = d1 * rstd * gr.y + br.y;
    o.z = d2 * rstd * gr.z + br.z;
    o.w = d3 * rstd * gr.w + br.w;
    *(float4*)(data + off) = o;
}

// -------- transpose+convert x2: fp32 [1024][1024] -> bf16 T (z picks W) ----
__global__ __launch_bounds__(256) void transpose_cvt2(
    const float* __restrict__ inA, const float* __restrict__ inB,
    unsigned short* __restrict__ outA, unsigned short* __restrict__ outB) {
    __shared__ unsigned short tile[32][33];
    const float* in = blockIdx.z ? inB : inA;
    unsigned short* outp = blockIdx.z ? outB : outA;
    int tid = threadIdx.x;
    int tx = tid & 31, ty = tid >> 5;          // 32 x 8
    int bx = blockIdx.x * 32, by = blockIdx.y * 32;
    #pragma unroll
    for (int r = 0; r < 32; r += 8)
        tile[ty + r][tx] = f2bf(in[(size_t)(by + ty + r) * 1024 + bx + tx]);
    __syncthreads();
    #pragma unroll
    for (int r = 0; r < 32; r += 8)
        outp[(size_t)(bx + ty + r) * 1024 + by + tx] = tile[tx][ty + r];
}

// ---------------- bf16 1024x1024 transpose ---------------------------------
__global__ __launch_bounds__(256) void transpose1024(
    const unsigned short* __restrict__ in, unsigned short* __restrict__ outp) {
    __shared__ unsigned short tile[32][33];
    int tid = threadIdx.x;
    int tx = tid & 31, ty = tid >> 5;
    int bx = blockIdx.x * 32, by = blockIdx.y * 32;
    #pragma unroll
    for (int r = 0; r < 32; r += 8)
        tile[ty + r][tx] = in[(size_t)(by + ty + r) * 1024 + bx + tx];
    __syncthreads();
    #pragma unroll
    for (int r = 0; r < 32; r += 8)
        outp[(size_t)(bx + ty + r) * 1024 + by + tx] = tile[tx][ty + r];
}

// ---------------- fused transpose + LN1: tokens -> X16 (MFMA-tiled) --------
// X16[b][sT][nT][nl][sl]: 16x16 tile (s-contiguous rows of 16), 512B/tile.
// element (b,s,n) at b*4194304 + ((s>>4)*64 + (n>>4))*256 + (n&15)*16 + (s&15)
__global__ __launch_bounds__(256) void transln16_kernel(
    const float* __restrict__ tok, const float* __restrict__ mu,
    const float* __restrict__ rs, const float* __restrict__ g,
    const float* __restrict__ bb, unsigned short* __restrict__ X16) {
    __shared__ unsigned short Lt[32][36];   // [n_local][s_local], pad 36 for 8B align
    int tid = threadIdx.x;
    int tx = tid & 31, ty = tid >> 5;      // 32 x 8
    int s0 = blockIdx.x * 32;              // seq within batch
    int n0 = blockIdx.y * 32;              // feature
    int b  = blockIdx.z;
    float gv = g[n0 + tx], bv = bb[n0 + tx];
    #pragma unroll
    for (int r = 0; r < 32; r += 8) {
        int grow = (b << 12) + s0 + ty + r;
        float v = tok[(size_t)grow * 1024 + n0 + tx];
        Lt[tx][ty + r] = f2bf((v - mu[grow]) * rs[grow] * gv + bv);
    }
    __syncthreads();
    int tt  = tid >> 6;                    // wave -> one 16x16 tile
    int sTl = tt >> 1, nTl = tt & 1;
    int idx = tid & 63;
    int nl  = idx >> 2, so4 = (idx & 3) << 2;   // 4 s-elems = 8B per thread
    uint2 v = *(const uint2*)&Lt[nTl * 16 + nl][sTl * 16 + so4];
    size_t off = (size_t)b * 4194304 +
        (((size_t)(((s0 >> 4) + sTl) * 64 + (n0 >> 4) + nTl)) << 8) +
        (nl << 4) + so4;
    *(uint2*)(X16 + off) = v;
}

// ---------------- small GEMM: Wfused = bf16(Wv @ Wo) -----------------------
__global__ __launch_bounds__(256) void gemm_small(
    const float* __restrict__ A32, const float* __restrict__ W32,
    unsigned short* __restrict__ C16) {
    const int K = 1024, N = 1024;
    __shared__ __align__(16) unsigned short As[64][40];
    __shared__ __align__(16) unsigned short Bs[64][40];
    int tid  = threadIdx.x;
    int lane = tid & 63, wv = tid >> 6;
    int lm   = lane & 15, quad = lane >> 4;
    int m0 = blockIdx.y * 64, n0 = blockIdx.x * 64;
    int srow = tid >> 2, scg = tid & 3;
    int bk   = tid >> 3, bn  = (tid & 7) * 8;

    f32x4 acc[4] = {};
    for (int k0 = 0; k0 < K; k0 += 32) {
        const float* ap = A32 + (size_t)(m0 + srow) * K + k0 + scg * 8;
        float4 p = *(const float4*)(ap);
        float4 q = *(const float4*)(ap + 4);
        union { uint4 u; unsigned short s[8]; } w;
        w.s[0]=f2bf(p.x); w.s[1]=f2bf(p.y); w.s[2]=f2bf(p.z); w.s[3]=f2bf(p.w);
        w.s[4]=f2bf(q.x); w.s[5]=f2bf(q.y); w.s[6]=f2bf(q.z); w.s[7]=f2bf(q.w);
        *(uint4*)&As[srow][scg * 8] = w.u;

        const float* wp = W32 + (size_t)(k0 + bk) * N + n0 + bn;
        float4 a = *(const float4*)wp, b = *(const float4*)(wp + 4);
        float wvv[8] = {a.x,a.y,a.z,a.w,b.x,b.y,b.z,b.w};
        #pragma unroll
        for (int e = 0; e < 8; ++e) Bs[bn + e][bk] = f2bf(wvv[e]);
        __syncthreads();
        bf16x8 af = *(const bf16x8*)&As[wv * 16 + lm][quad * 8];
        #pragma unroll
        for (int t = 0; t < 4; ++t) {
            bf16x8 bfr = *(const bf16x8*)&Bs[t * 16 + lm][quad * 8];
            acc[t] = __builtin_amdgcn_mfma_f32_16x16x32_bf16(af, bfr, acc[t], 0, 0, 0);
        }
        __syncthreads();
    }
    #pragma unroll
    for (int t = 0; t < 4; ++t) {
        int col = n0 + t * 16 + lm;
        #pragma unroll
        for (int r = 0; r < 4; ++r) {
            int row = m0 + wv * 16 + quad * 4 + r;
            C16[(size_t)row * N + col] = f2bf(acc[t][r]);
        }
    }
}

// ---------------- 128x128 GEMM, BK=64: C = A[bf16] @ BT[bf16]^T ------------
// BK 32->64: barrier pairs halved (32->16), 8 async stages per drain instead
// of 4 -> staging latency amortized over 32 MFMAs. LDS 32KB, still 4 blk/CU.
template <bool EPI>
__global__ __launch_bounds__(256) void gemm128(
    const unsigned short* __restrict__ A, const unsigned short* __restrict__ BT,
    unsigned short* __restrict__ C16, float* __restrict__ Cres,
    const float* __restrict__ tok) {
    const int K = 1024, N = 1024;
    __shared__ __align__(16) unsigned short As[8192];  // 8 octets x 128 rows x 8
    __shared__ __align__(16) unsigned short Bs[8192];
    int tid = threadIdx.x, lane = tid & 63, wv = tid >> 6;
    int lm = lane & 15, quad = lane >> 4;
    int wr = wv >> 1, wc = wv & 1;
    // XCD swizzle (dispatch order: x fastest). 1024 = 8*128, bijective.
    int flat = blockIdx.y * 8 + blockIdx.x;
    int logical = ((flat & 7) << 7) | (flat >> 3);
    int m0 = (logical >> 3) * 128, n0 = (logical & 7) * 128;

    f32x4 acc[4][4] = {};

    const unsigned short* ga0 = A  + (size_t)(m0 + lane) * K + wv * 8;
    const unsigned short* ga1 = A  + (size_t)(m0 + 64 + lane) * K + wv * 8;
    const unsigned short* gb0 = BT + (size_t)(n0 + lane) * K + wv * 8;
    const unsigned short* gb1 = BT + (size_t)(n0 + 64 + lane) * K + wv * 8;
    unsigned short* la0 = &As[wv * 1024 + lane * 8];
    unsigned short* la1 = &As[wv * 1024 + 512 + lane * 8];
    unsigned short* lb0 = &Bs[wv * 1024 + lane * 8];
    unsigned short* lb1 = &Bs[wv * 1024 + 512 + lane * 8];

    for (int k0 = 0; k0 < K; k0 += 64) {
        gld_lds16(ga0 + k0, la0);
        gld_lds16(ga1 + k0, la1);
        gld_lds16(ga0 + k0 + 32, la0 + 4096);
        gld_lds16(ga1 + k0 + 32, la1 + 4096);
        gld_lds16(gb0 + k0, lb0);
        gld_lds16(gb1 + k0, lb1);
        gld_lds16(gb0 + k0 + 32, lb0 + 4096);
        gld_lds16(gb1 + k0 + 32, lb1 + 4096);
        __syncthreads();
        #pragma unroll
        for (int ks = 0; ks < 2; ++ks) {
            bf16x8 af[4], bfr[4];
            #pragma unroll
            for (int t = 0; t < 4; ++t) {
                af[t]  = *(const bf16x8*)&As[ks * 4096 + quad * 1024 + (wr * 64 + t * 16 + lm) * 8];
                bfr[t] = *(const bf16x8*)&Bs[ks * 4096 + quad * 1024 + (wc * 64 + t * 16 + lm) * 8];
            }
            #pragma unroll
            for (int mt = 0; mt < 4; ++mt)
                #pragma unroll
                for (int nt = 0; nt < 4; ++nt)
                    acc[mt][nt] = __builtin_amdgcn_mfma_f32_16x16x32_bf16(
                        af[mt], bfr[nt], acc[mt][nt], 0, 0, 0);
        }
        __syncthreads();
    }
    #pragma unroll
    for (int mt = 0; mt < 4; ++mt) {
        #pragma unroll
        for (int nt = 0; nt < 4; ++nt) {
            int col = n0 + wc * 64 + nt * 16 + lm;
            #pragma unroll
            for (int r = 0; r < 4; ++r) {
                int row = m0 + wr * 64 + mt * 16 + quad * 4 + r;
                size_t idx = (size_t)row * N + col;
                if (EPI) Cres[idx] = tok[idx] + 0.1f * acc[mt][nt][r];
                else     C16[idx]  = f2bf(acc[mt][nt][r]);
            }
        }
    }
}

// ------- merged Q/K GEMM, BK=64: [Qb|Kb] = xb @ [WqT;WkT]^T  (N=2048) ------
__global__ __launch_bounds__(256) void gemm128qk(
    const unsigned short* __restrict__ A, const unsigned short* __restrict__ BT,
    unsigned short* __restrict__ Qb, unsigned short* __restrict__ Kb) {
    const int K = 1024;
    __shared__ __align__(16) unsigned short As[8192];
    __shared__ __align__(16) unsigned short Bs[8192];
    int tid = threadIdx.x, lane = tid & 63, wv = tid >> 6;
    int lm = lane & 15, quad = lane >> 4;
    int wr = wv >> 1, wc = wv & 1;
    int flat = blockIdx.y * 16 + blockIdx.x;
    int logical = ((flat & 7) << 8) | (flat >> 3);
    int m0 = (logical >> 4) * 128, n0 = (logical & 15) * 128;

    f32x4 acc[4][4] = {};

    const unsigned short* ga0 = A  + (size_t)(m0 + lane) * K + wv * 8;
    const unsigned short* ga1 = A  + (size_t)(m0 + 64 + lane) * K + wv * 8;
    const unsigned short* gb0 = BT + (size_t)(n0 + lane) * K + wv * 8;
    const unsigned short* gb1 = BT + (size_t)(n0 + 64 + lane) * K + wv * 8;
    unsigned short* la0 = &As[wv * 1024 + lane * 8];
    unsigned short* la1 = &As[wv * 1024 + 512 + lane * 8];
    unsigned short* lb0 = &Bs[wv * 1024 + lane * 8];
    unsigned short* lb1 = &Bs[wv * 1024 + 512 + lane * 8];

    for (int k0 = 0; k0 < K; k0 += 64) {
        gld_lds16(ga0 + k0, la0);
        gld_lds16(ga1 + k0, la1);
        gld_lds16(ga0 + k0 + 32, la0 + 4096);
        gld_lds16(ga1 + k0 + 32, la1 + 4096);
        gld_lds16(gb0 + k0, lb0);
        gld_lds16(gb1 + k0, lb1);
        gld_lds16(gb0 + k0 + 32, lb0 + 4096);
        gld_lds16(gb1 + k0 + 32, lb1 + 4096);
        __syncthreads();
        #pragma unroll
        for (int ks = 0; ks < 2; ++ks) {
            bf16x8 af[4], bfr[4];
            #pragma unroll
            for (int t = 0; t < 4; ++t) {
                af[t]  = *(const bf16x8*)&As[ks * 4096 + quad * 1024 + (wr * 64 + t * 16 + lm) * 8];
                bfr[t] = *(const bf16x8*)&Bs[ks * 4096 + quad * 1024 + (wc * 64 + t * 16 + lm) * 8];
            }
            #pragma unroll
            for (int mt = 0; mt < 4; ++mt)
                #pragma unroll
                for (int nt = 0; nt < 4; ++nt)
                    acc[mt][nt] = __builtin_amdgcn_mfma_f32_16x16x32_bf16(
                        af[mt], bfr[nt], acc[mt][nt], 0, 0, 0);
        }
        __syncthreads();
    }
    unsigned short* dst = (n0 < 1024) ? Qb : Kb;
    int nbase = (n0 < 1024) ? n0 : (n0 - 1024);
    #pragma unroll
    for (int mt = 0; mt < 4; ++mt) {
        #pragma unroll
        for (int nt = 0; nt < 4; ++nt) {
            int col = nbase + wc * 64 + nt * 16 + lm;
            #pragma unroll
            for (int r = 0; r < 4; ++r) {
                int row = m0 + wr * 64 + mt * 16 + quad * 4 + r;
                dst[(size_t)row * 1024 + col] = f2bf(acc[mt][nt][r]);
            }
        }
    }
}

// ---------------- MFMA sparse attention: 16 queries per block --------------
// (round-8 code, frozen: 227-229us, occ 20%, VGPR 128.)
#define NT_MAX 48
#define SCROW  776    // 48*16 + 8 pad (elems)
__global__ __launch_bounds__(256) void attn16_kernel(
    const unsigned short* __restrict__ Q, const unsigned short* __restrict__ K,
    const unsigned short* __restrict__ XT, unsigned short* __restrict__ Ao) {
    __shared__ __align__(16) unsigned short Ps[16 * SCROW];
    int tid = threadIdx.x, lane = tid & 63, wv = tid >> 6;
    int lm = lane & 15, quad = lane >> 4;
    int bxr = blockIdx.x;
    int xcd = bxr & 7;
    int sl  = bxr >> 3;                  // 0..127 slot within XCD
    int batch = xcd >> 1;
    int ptyp  = xcd & 1;
    int g = sl & 31, j = sl >> 5;        // CU 0..31 (round-robin), seq 0..3
    int t;
    if (ptyp) t = (j == 0) ? 64 + g : (j == 1) ? 191 - g
                 : (j == 2) ? 96 + g : 159 - g;
    else      t = (j == 0) ? g       : (j == 1) ? 63 - g
                 : (j == 2) ? 192 + g : 255 - g;
    int bx = batch * 256 + t;
    int b  = bx >> 8;
    int i0 = (bx & 255) << 4;
    int rowbase = (b << 12) + i0;
    int wlo = i0 - 256; if (wlo < 0) wlo = 0;
    int nwin = ((i0 - wlo) >> 4) + 1;
    int tmax = (i0 - 16) / 128;              // trunc; i0=0 -> 0
    int nstr = tmax - 2; if (nstr < 0) nstr = 0;
    int nglob = (wlo > 0) ? 1 : 0;
    int ntiles = nwin + nstr + nglob;
    int ntp = (ntiles + 3) & ~3;

    const unsigned short* Qg = Q + (size_t)(rowbase + lm) * 1024 + quad * 8;

    // ---- phase 1: score tiles (QK^T), masked write to Ps ----
    const unsigned short* Kbp = K + (((size_t)b << 12) << 10);
    for (int tg = wv * 4; tg < ntp; tg += 16) {
        f32x4 acc[4] = {};
        int tb[4];
        #pragma unroll
        for (int c = 0; c < 4; ++c) {
            int t2 = tg + c, base = 0;
            if (t2 < nwin) base = wlo + (t2 << 4);
            else if (t2 - nwin < nstr) base = i0 - 128 * (3 + (t2 - nwin));
            tb[c] = base;                     // global / padded -> 0
        }
        for (int k0 = 0; k0 < 1024; k0 += 32) {
            bf16x8 a = *(const bf16x8*)(Qg + k0);
            #pragma unroll
            for (int c = 0; c < 4; ++c) {
                bf16x8 bb = *(const bf16x8*)(Kbp +
                    (size_t)(tb[c] + lm) * 1024 + k0 + quad * 8);
                acc[c] = __builtin_amdgcn_mfma_f32_16x16x32_bf16(a, bb, acc[c], 0, 0, 0);
            }
        }
        #pragma unroll
        for (int c = 0; c < 4; ++c) {
            int t2 = tg + c;
            int j2 = tb[c] + lm;
            bool pad = (t2 >= ntiles);
            #pragma unroll
            for (int r = 0; r < 4; ++r) {
                int i = i0 + quad * 4 + r;
                int diff = i - j2;
                bool ok = !pad && (j2 <= i) &&
                          (diff < 256 || (diff & 127) == 0 || j2 < 16);
                Ps[(quad * 4 + r) * SCROW + (t2 << 4) + lm] =
                    f2bf(ok ? acc[c][r] : -1e30f);
            }
        }
    }
    __syncthreads();

    // ---- phase 2: softmax on rows wv*4 .. wv*4+3 ----
    int ncol = ntp << 4;
    for (int q = wv * 4; q < wv * 4 + 4; ++q) {
        unsigned short* row = &Ps[q * SCROW];
        float mx = -1e30f;
        for (int c = lane; c < ncol; c += 64) mx = fmaxf(mx, b2f(row[c]));
        #pragma unroll
        for (int m = 32; m >= 1; m >>= 1) mx = fmaxf(mx, __shfl_xor(mx, m, 64));
        float sm = 0.f;
        for (int c = lane; c < ncol; c += 64)
            sm += __expf(SCALE_F * (b2f(row[c]) - mx));
        #pragma unroll
        for (int m = 32; m >= 1; m >>= 1) sm += __shfl_xor(sm, m, 64);
        float inv = 1.0f / sm;
        for (int c = lane; c < ncol; c += 64)
            row[c] = f2bf(__expf(SCALE_F * (b2f(row[c]) - mx)) * inv);
    }
    __syncthreads();

    // ---- phase 3: O = P @ X16  (wave owns 256 cols = n-tiles nT0..nT0+15) --
    int n0w = wv * 256;
    int nT0 = wv << 4;
    const unsigned short* Xb = XT + (size_t)b * 4194304;
    int octet = quad & 1, tsel = quad >> 1;
    f32x4 oacc[16] = {};
    int nch = ntp >> 1;
    for (int c = 0; c < nch; ++c) {
        int t0 = 2 * c, t1 = 2 * c + 1;
        int b0 = (t0 < nwin) ? wlo + (t0 << 4)
               : ((t0 - nwin < nstr) ? i0 - 128 * (3 + t0 - nwin) : 0);
        int b1 = (t1 < nwin) ? wlo + (t1 << 4)
               : ((t1 - nwin < nstr) ? i0 - 128 * (3 + t1 - nwin) : 0);
        bf16x8 a = *(const bf16x8*)&Ps[lm * SCROW + (c << 5) + quad * 8];
        int sT = (tsel ? b1 : b0) >> 4;
        const unsigned short* xp = Xb + (((size_t)(sT * 64 + nT0)) << 8)
                                      + (lm << 4) + (octet << 3);
        #pragma unroll
        for (int nt = 0; nt < 16; ++nt) {
            bf16x8 bb2 = *(const bf16x8*)(xp + (nt << 8));
            oacc[nt] = __builtin_amdgcn_mfma_f32_16x16x32_bf16(a, bb2, oacc[nt], 0, 0, 0);
        }
    }
    #pragma unroll
    for (int nt = 0; nt < 16; ++nt) {
        int col = n0w + nt * 16 + lm;
        #pragma unroll
        for (int r = 0; r < 4; ++r) {
            int row = rowbase + quad * 4 + r;
            Ao[(size_t)row * 1024 + col] = f2bf(oacc[nt][r]);
        }
    }
}

// ---------------------------------------------------------------------------
extern "C" void kernel_launch(void* const* d_in, const int* in_sizes, int n_in,
                              void* d_out, int out_size, void* d_ws, size_t ws_size,
                              hipStream_t stream) {
    const float* tokens = (const float*)d_in[0];
    const float* Wq = (const float*)d_in[1];
    const float* Wk = (const float*)d_in[2];
    const float* Wv = (const float*)d_in[3];
    const float* Wo = (const float*)d_in[4];
    const float* g1 = (const float*)d_in[5];
    const float* b1 = (const float*)d_in[6];
    const float* g2 = (const float*)d_in[7];
    const float* b2 = (const float*)d_in[8];
    float* out = (float*)d_out;
    char* ws = (char*)d_ws;

    // ws (41MB):
    //   mu @0 (64KB), rs @64KB, WqT @1MB, WkT @3MB (contiguous with WqT ->
    //   single [2048][1024] BT for merged QK gemm), Wfused @5MB, WfT @7MB,
    //   Q bf16 @9MB..41MB  -> attnX written in place
    // d_out (64MB fp32) as staging:
    //   xb bf16 @[0:32MB)  -> overwritten by X16 after QK gemm
    //   K  bf16 @[32:64MB)
    // then out-gemm overwrites all of d_out with fp32 residual; LN2 in place.
    const size_t MB = 1048576;
    float* mu = (float*)(ws);
    float* rs = (float*)(ws + 65536);
    unsigned short* WqT    = (unsigned short*)(ws + 1 * MB);
    unsigned short* WkT    = (unsigned short*)(ws + 3 * MB);
    unsigned short* Wfused = (unsigned short*)(ws + 5 * MB);
    unsigned short* WfT    = (unsigned short*)(ws + 7 * MB);
    unsigned short* Qb     = (unsigned short*)(ws + 9 * MB);
    unsigned short* xb     = (unsigned short*)d_out;
    unsigned short* X16    = (unsigned short*)d_out;   // overwrites xb later
    unsigned short* Kb     = (unsigned short*)d_out + 16777216;
    unsigned short* attnX  = Qb;

    dim3 b256(256);
    const int ROWS = 4 * S_LEN;           // 16384
    dim3 tg2(32, 32, 2);
    dim3 tg(32, 32);
    dim3 gsmall(16, 16);
    dim3 g128(8, 128);                    // N/128 x M/128 (out-gemm)
    dim3 gqk(16, 128);                    // merged QK: N=2048
    dim3 gtl(128, 32, 4);                 // transLN16: s-tiles x n-tiles x batch

    // 1. LN1: stats + xb (row-major)
    ln_full_kernel<<<ROWS, b256, 0, stream>>>(tokens, mu, rs, g1, b1, xb);
    // 2. weight prep
    transpose_cvt2<<<tg2, b256, 0, stream>>>(Wq, Wk, WqT, WkT);
    gemm_small<<<gsmall, b256, 0, stream>>>(Wv, Wo, Wfused);
    transpose1024<<<tg, b256, 0, stream>>>(Wfused, WfT);
    // 3. [Q|K] = xb @ [Wq|Wk]  (merged, one A-stream, BK=64)
    gemm128qk<<<gqk, b256, 0, stream>>>(xb, WqT, Qb, Kb);
    // 4. X16 = tiled(LN1(tokens)) per batch (overwrites xb; reads tokens)
    transln16_kernel<<<gtl, b256, 0, stream>>>(tokens, mu, rs, g1, b1, X16);
    // 5. MFMA sparse attention (attnX over Q)
    attn16_kernel<<<1024, b256, 0, stream>>>(Qb, Kb, X16, attnX);
    // 6. out = tokens + 0.1*(attnX @ Wfused)  (BK=64)
    gemm128<true><<<g128, b256, 0, stream>>>(attnX, WfT, nullptr, out, tokens);
    // 7. LN2 in place
    ln2_inplace_kernel<<<ROWS, b256, 0, stream>>>(out, g2, b2);
}